// Round 1
// baseline (2827.039 us; speedup 1.0000x reference)
//
#include <hip/hip_runtime.h>
#include <cmath>

// Problem constants (fixed by setup_inputs)
constexpr int NB   = 8;     // batch
constexpr int LSEQ = 8192;  // sequence length
constexpr int DIN  = 256;
constexpr int DH   = 512;
constexpr int DOUT = 256;
constexpr int CHK  = 1024;  // chunk size
constexpr int NCHK = LSEQ / CHK; // 8

constexpr int LDT = 68;     // padded LDS tile leading dim (68*4B = 272B, 16B-aligned rows)

// ---------------------------------------------------------------------------
// Fused dual NT GEMM: G = X @ W0^T, H = X @ W2^T   (M=CHK, N=DH, K=DIN)
// MODE 0: write act = silu(G)*H to out0.   MODE 1: write G->out0, H->out1.
// ---------------------------------------------------------------------------
template<int MODE>
__global__ __launch_bounds__(256)
void k_gh(const float* __restrict__ x, const float* __restrict__ w0,
          const float* __restrict__ w2, float* __restrict__ out0,
          float* __restrict__ out1, int chunk)
{
  __shared__ alignas(16) float As [16][LDT];
  __shared__ alignas(16) float B0s[16][LDT];
  __shared__ alignas(16) float B1s[16][LDT];

  const int b  = blockIdx.z;
  const int m0 = blockIdx.y * 64;
  const int n0 = blockIdx.x * 64;
  const float* X  = x  + ((size_t)b * LSEQ + (size_t)chunk * CHK) * DIN;
  const float* W0 = w0 + (size_t)b * DH * DIN;
  const float* W2 = w2 + (size_t)b * DH * DIN;

  const int tid = threadIdx.x;
  const int tx = tid & 15, ty = tid >> 4;
  const int lr = tid >> 2;          // 0..63 (row of 64)
  const int lc = (tid & 3) << 2;    // 0,4,8,12 (k offset)

  float acc0[4][4] = {}; float acc1[4][4] = {};

  for (int k0 = 0; k0 < DIN; k0 += 16) {
    float4 av = *(const float4*)&X [(size_t)(m0 + lr) * DIN + k0 + lc];
    float4 b0 = *(const float4*)&W0[(size_t)(n0 + lr) * DIN + k0 + lc];
    float4 b1 = *(const float4*)&W2[(size_t)(n0 + lr) * DIN + k0 + lc];
    As [lc+0][lr] = av.x; As [lc+1][lr] = av.y; As [lc+2][lr] = av.z; As [lc+3][lr] = av.w;
    B0s[lc+0][lr] = b0.x; B0s[lc+1][lr] = b0.y; B0s[lc+2][lr] = b0.z; B0s[lc+3][lr] = b0.w;
    B1s[lc+0][lr] = b1.x; B1s[lc+1][lr] = b1.y; B1s[lc+2][lr] = b1.z; B1s[lc+3][lr] = b1.w;
    __syncthreads();
#pragma unroll
    for (int kk = 0; kk < 16; ++kk) {
      float4 a4 = *(const float4*)&As [kk][ty * 4];
      float4 p4 = *(const float4*)&B0s[kk][tx * 4];
      float4 q4 = *(const float4*)&B1s[kk][tx * 4];
      const float a[4] = {a4.x, a4.y, a4.z, a4.w};
      const float p[4] = {p4.x, p4.y, p4.z, p4.w};
      const float qq[4]= {q4.x, q4.y, q4.z, q4.w};
#pragma unroll
      for (int i = 0; i < 4; ++i)
#pragma unroll
        for (int j = 0; j < 4; ++j) {
          acc0[i][j] += a[i] * p[j];
          acc1[i][j] += a[i] * qq[j];
        }
    }
    __syncthreads();
  }
#pragma unroll
  for (int i = 0; i < 4; ++i) {
    const int m = m0 + ty * 4 + i;
#pragma unroll
    for (int j = 0; j < 4; ++j) {
      const int n = n0 + tx * 4 + j;
      const size_t o = ((size_t)b * CHK + m) * DH + n;
      if (MODE == 0) {
        const float g = acc0[i][j], h = acc1[i][j];
        const float s = 1.f / (1.f + expf(-g));
        out0[o] = g * s * h;
      } else {
        out0[o] = acc0[i][j];
        out1[o] = acc1[i][j];
      }
    }
  }
}

// ---------------------------------------------------------------------------
// NT GEMM: out_chunk = act @ w1^T  (M=CHK, N=DOUT, K=DH), writes final output
// ---------------------------------------------------------------------------
__global__ __launch_bounds__(256)
void k_out(const float* __restrict__ act, const float* __restrict__ w1,
           float* __restrict__ out, int chunk)
{
  __shared__ alignas(16) float As[16][LDT];
  __shared__ alignas(16) float Bs[16][LDT];

  const int b  = blockIdx.z;
  const int m0 = blockIdx.y * 64;
  const int n0 = blockIdx.x * 64;
  const float* A = act + (size_t)b * CHK * DH;
  const float* W = w1  + (size_t)b * DOUT * DH;

  const int tid = threadIdx.x;
  const int tx = tid & 15, ty = tid >> 4;
  const int lr = tid >> 2;
  const int lc = (tid & 3) << 2;

  float acc[4][4] = {};

  for (int k0 = 0; k0 < DH; k0 += 16) {
    float4 av = *(const float4*)&A[(size_t)(m0 + lr) * DH + k0 + lc];
    float4 bv = *(const float4*)&W[(size_t)(n0 + lr) * DH + k0 + lc];
    As[lc+0][lr] = av.x; As[lc+1][lr] = av.y; As[lc+2][lr] = av.z; As[lc+3][lr] = av.w;
    Bs[lc+0][lr] = bv.x; Bs[lc+1][lr] = bv.y; Bs[lc+2][lr] = bv.z; Bs[lc+3][lr] = bv.w;
    __syncthreads();
#pragma unroll
    for (int kk = 0; kk < 16; ++kk) {
      float4 a4 = *(const float4*)&As[kk][ty * 4];
      float4 b4 = *(const float4*)&Bs[kk][tx * 4];
      const float a[4] = {a4.x, a4.y, a4.z, a4.w};
      const float p[4] = {b4.x, b4.y, b4.z, b4.w};
#pragma unroll
      for (int i = 0; i < 4; ++i)
#pragma unroll
        for (int j = 0; j < 4; ++j) acc[i][j] += a[i] * p[j];
    }
    __syncthreads();
  }
#pragma unroll
  for (int i = 0; i < 4; ++i) {
    const int m = m0 + ty * 4 + i;
#pragma unroll
    for (int j = 0; j < 4; ++j) {
      const int n = n0 + tx * 4 + j;
      out[((size_t)b * LSEQ + (size_t)chunk * CHK + m) * DOUT + n] = acc[i][j];
    }
  }
}

// ---------------------------------------------------------------------------
// NN GEMM: dh = v_chunk @ w1   (M=CHK, N=DH, K=DOUT)
// ---------------------------------------------------------------------------
__global__ __launch_bounds__(256)
void k_dh(const float* __restrict__ v, const float* __restrict__ w1,
          float* __restrict__ dh, int chunk)
{
  __shared__ alignas(16) float As[16][LDT];
  __shared__ alignas(16) float Bs[16][LDT];

  const int b  = blockIdx.z;
  const int m0 = blockIdx.y * 64;
  const int n0 = blockIdx.x * 64;
  const float* V = v  + ((size_t)b * LSEQ + (size_t)chunk * CHK) * DOUT;
  const float* W = w1 + (size_t)b * DOUT * DH;

  const int tid = threadIdx.x;
  const int tx = tid & 15, ty = tid >> 4;
  const int lr = tid >> 2;
  const int lc = (tid & 3) << 2;
  const int bk = tid >> 4;          // 0..15 (k row for B tile)
  const int bc = (tid & 15) << 2;   // 0..60 (n col for B tile)

  float acc[4][4] = {};

  for (int k0 = 0; k0 < DOUT; k0 += 16) {
    float4 av = *(const float4*)&V[(size_t)(m0 + lr) * DOUT + k0 + lc];
    float4 bv = *(const float4*)&W[(size_t)(k0 + bk) * DH + n0 + bc];
    As[lc+0][lr] = av.x; As[lc+1][lr] = av.y; As[lc+2][lr] = av.z; As[lc+3][lr] = av.w;
    *(float4*)&Bs[bk][bc] = bv;
    __syncthreads();
#pragma unroll
    for (int kk = 0; kk < 16; ++kk) {
      float4 a4 = *(const float4*)&As[kk][ty * 4];
      float4 b4 = *(const float4*)&Bs[kk][tx * 4];
      const float a[4] = {a4.x, a4.y, a4.z, a4.w};
      const float p[4] = {b4.x, b4.y, b4.z, b4.w};
#pragma unroll
      for (int i = 0; i < 4; ++i)
#pragma unroll
        for (int j = 0; j < 4; ++j) acc[i][j] += a[i] * p[j];
    }
    __syncthreads();
  }
#pragma unroll
  for (int i = 0; i < 4; ++i) {
    const int m = m0 + ty * 4 + i;
#pragma unroll
    for (int j = 0; j < 4; ++j) {
      const int n = n0 + tx * 4 + j;
      dh[((size_t)b * CHK + m) * DH + n] = acc[i][j];
    }
  }
}

// ---------------------------------------------------------------------------
// Elementwise backprop through SwiGLU, pre-scaled by per-row lr.
// In-place:  g <- dgba*l0,  hb <- dhbm*l2,  dh <- hidden*l1
// ---------------------------------------------------------------------------
__global__ __launch_bounds__(256)
void k_bwd(float* __restrict__ g, float* __restrict__ hb, float* __restrict__ dh,
           const float* __restrict__ lr0, const float* __restrict__ lr1,
           const float* __restrict__ lr2, int chunk)
{
  const size_t i4 = (size_t)blockIdx.x * 256 + threadIdx.x;
  const size_t base = i4 * 4;                 // 4 consecutive elements, same row
  const int h0 = (int)(base % DH);
  const size_t bc = base / DH;
  const int c = (int)(bc % CHK);
  const int b = (int)(bc / CHK);
  (void)h0;
  const size_t li = (size_t)b * LSEQ + (size_t)chunk * CHK + c;
  const float l0 = lr0[li], l1 = lr1[li], l2 = lr2[li];

  float4 g4  = *(float4*)&g [base];
  float4 h4  = *(float4*)&hb[base];
  float4 d4  = *(float4*)&dh[base];
  float go[4], ho[4], dho[4];
  const float gv[4] = {g4.x, g4.y, g4.z, g4.w};
  const float hv[4] = {h4.x, h4.y, h4.z, h4.w};
  const float dv[4] = {d4.x, d4.y, d4.z, d4.w};
#pragma unroll
  for (int t = 0; t < 4; ++t) {
    const float sig = 1.f / (1.f + expf(-gv[t]));
    const float sg  = gv[t] * sig;
    const float hidden = sg * hv[t];
    const float dhbm   = dv[t] * sg;
    const float dgrad  = dv[t] * hv[t];
    const float dgba   = dgrad * sig * (1.f + gv[t] * (1.f - sig));
    go[t]  = dgba * l0;
    ho[t]  = dhbm * l2;
    dho[t] = hidden * l1;
  }
  *(float4*)&g [base] = make_float4(go[0], go[1], go[2], go[3]);
  *(float4*)&hb[base] = make_float4(ho[0], ho[1], ho[2], ho[3]);
  *(float4*)&dh[base] = make_float4(dho[0], dho[1], dho[2], dho[3]);
}

// ---------------------------------------------------------------------------
// TN GEMM (+= into main weights): wm1 += A1^T @ B, (DUAL: wm2 += A2^T @ B)
// A[k,m] (lda), B[k,n] (ldb), K=CHK. Base pointers already at chunk start;
// per-batch strides sA, sB.
// ---------------------------------------------------------------------------
template<bool DUAL>
__global__ __launch_bounds__(256)
void k_dw(const float* __restrict__ A1, const float* __restrict__ A2,
          const float* __restrict__ Bm, float* __restrict__ wm1,
          float* __restrict__ wm2,
          int lda, size_t sA, int ldb, size_t sB, int Mdim, int Ndim)
{
  __shared__ alignas(16) float As1[16][LDT];
  __shared__ alignas(16) float As2[16][LDT];
  __shared__ alignas(16) float Bs [16][LDT];

  const int b  = blockIdx.z;
  const int m0 = blockIdx.y * 64;
  const int n0 = blockIdx.x * 64;
  const float* A1b = A1 + (size_t)b * sA;
  const float* A2b = DUAL ? (A2 + (size_t)b * sA) : nullptr;
  const float* Bb  = Bm + (size_t)b * sB;

  const int tid = threadIdx.x;
  const int tx = tid & 15, ty = tid >> 4;
  const int bk = tid >> 4;          // 0..15
  const int bc = (tid & 15) << 2;   // 0..60

  float acc0[4][4] = {}; float acc1[4][4] = {};

  for (int k0 = 0; k0 < CHK; k0 += 16) {
    float4 a1 = *(const float4*)&A1b[(size_t)(k0 + bk) * lda + m0 + bc];
    *(float4*)&As1[bk][bc] = a1;
    if (DUAL) {
      float4 a2 = *(const float4*)&A2b[(size_t)(k0 + bk) * lda + m0 + bc];
      *(float4*)&As2[bk][bc] = a2;
    }
    float4 bv = *(const float4*)&Bb[(size_t)(k0 + bk) * ldb + n0 + bc];
    *(float4*)&Bs[bk][bc] = bv;
    __syncthreads();
#pragma unroll
    for (int kk = 0; kk < 16; ++kk) {
      float4 a4 = *(const float4*)&As1[kk][ty * 4];
      float4 b4 = *(const float4*)&Bs [kk][tx * 4];
      const float a[4] = {a4.x, a4.y, a4.z, a4.w};
      const float p[4] = {b4.x, b4.y, b4.z, b4.w};
      if (DUAL) {
        float4 c4 = *(const float4*)&As2[kk][ty * 4];
        const float a2[4] = {c4.x, c4.y, c4.z, c4.w};
#pragma unroll
        for (int i = 0; i < 4; ++i)
#pragma unroll
          for (int j = 0; j < 4; ++j) {
            acc0[i][j] += a[i]  * p[j];
            acc1[i][j] += a2[i] * p[j];
          }
      } else {
#pragma unroll
        for (int i = 0; i < 4; ++i)
#pragma unroll
          for (int j = 0; j < 4; ++j) acc0[i][j] += a[i] * p[j];
      }
    }
    __syncthreads();
  }
#pragma unroll
  for (int i = 0; i < 4; ++i) {
    const int m = m0 + ty * 4 + i;
#pragma unroll
    for (int j = 0; j < 4; ++j) {
      const int n = n0 + tx * 4 + j;
      const size_t o = ((size_t)b * Mdim + m) * Ndim + n;
      wm1[o] += acc0[i][j];
      if (DUAL) wm2[o] += acc1[i][j];
    }
  }
}

// ---------------------------------------------------------------------------
// Row dispatch helper for the 3 weights (rows: [NB*DH w0][NB*DOUT w1][NB*DH w2])
// ---------------------------------------------------------------------------
constexpr int NROWS0 = NB * DH;    // 4096
constexpr int NROWS1 = NB * DOUT;  // 2048
constexpr int NROWS_TOT = NROWS0 + NROWS1 + NROWS0; // 10240

// init: wm=w, wc=w, wn=||w_row||
__global__ __launch_bounds__(64)
void k_init(const float* __restrict__ w0, const float* __restrict__ w1,
            const float* __restrict__ w2,
            float* __restrict__ w0m, float* __restrict__ w1m, float* __restrict__ w2m,
            float* __restrict__ w0c, float* __restrict__ w1c, float* __restrict__ w2c,
            float* __restrict__ wn)
{
  const int row = blockIdx.x;
  const float* src; float* m; float* c; float* nrm; int len; int r;
  if (row < NROWS0)               { r = row;                  src = w0; m = w0m; c = w0c; nrm = wn;                  len = DIN; }
  else if (row < NROWS0 + NROWS1) { r = row - NROWS0;         src = w1; m = w1m; c = w1c; nrm = wn + NROWS0;         len = DH;  }
  else                            { r = row - NROWS0 - NROWS1;src = w2; m = w2m; c = w2c; nrm = wn + NROWS0 + NROWS1;len = DIN; }
  const float* s = src + (size_t)r * len;
  float* md = m + (size_t)r * len;
  float* cd = c + (size_t)r * len;
  float ss = 0.f;
  for (int i = threadIdx.x; i < len; i += 64) {
    const float v = s[i];
    md[i] = v; cd[i] = v;
    ss += v * v;
  }
#pragma unroll
  for (int off = 32; off > 0; off >>= 1) ss += __shfl_down(ss, off);
  if (threadIdx.x == 0) nrm[r] = sqrtf(ss);
}

// renorm: wc = wm / (||wm_row|| + eps) * wn
__global__ __launch_bounds__(64)
void k_renorm(const float* __restrict__ w0m, const float* __restrict__ w1m,
              const float* __restrict__ w2m,
              float* __restrict__ w0c, float* __restrict__ w1c, float* __restrict__ w2c,
              const float* __restrict__ wn)
{
  const int row = blockIdx.x;
  const float* m; float* c; const float* nrm; int len; int r;
  if (row < NROWS0)               { r = row;                   m = w0m; c = w0c; nrm = wn;                   len = DIN; }
  else if (row < NROWS0 + NROWS1) { r = row - NROWS0;          m = w1m; c = w1c; nrm = wn + NROWS0;          len = DH;  }
  else                            { r = row - NROWS0 - NROWS1; m = w2m; c = w2c; nrm = wn + NROWS0 + NROWS1; len = DIN; }
  const float* s = m + (size_t)r * len;
  float* d = c + (size_t)r * len;
  float ss = 0.f;
  for (int i = threadIdx.x; i < len; i += 64) { const float v = s[i]; ss += v * v; }
#pragma unroll
  for (int off = 32; off > 0; off >>= 1) ss += __shfl_down(ss, off);
  ss = __shfl(ss, 0);
  const float scale = nrm[r] / (sqrtf(ss) + 1e-5f);
  for (int i = threadIdx.x; i < len; i += 64) d[i] = s[i] * scale;
}

// ---------------------------------------------------------------------------
extern "C" void kernel_launch(void* const* d_in, const int* in_sizes, int n_in,
                              void* d_out, int out_size, void* d_ws, size_t ws_size,
                              hipStream_t stream)
{
  const float* w0  = (const float*)d_in[0];
  const float* w1  = (const float*)d_in[1];
  const float* w2  = (const float*)d_in[2];
  const float* q   = (const float*)d_in[3];
  const float* k   = (const float*)d_in[4];
  const float* v   = (const float*)d_in[5];
  const float* lr0 = (const float*)d_in[6];
  const float* lr1 = (const float*)d_in[7];
  const float* lr2 = (const float*)d_in[8];
  float* out = (float*)d_out;

  float* ws = (float*)d_ws;
  size_t off = 0;
  float* w0c = ws + off; off += (size_t)NB * DH * DIN;
  float* w1c = ws + off; off += (size_t)NB * DOUT * DH;
  float* w2c = ws + off; off += (size_t)NB * DH * DIN;
  float* w0m = ws + off; off += (size_t)NB * DH * DIN;
  float* w1m = ws + off; off += (size_t)NB * DOUT * DH;
  float* w2m = ws + off; off += (size_t)NB * DH * DIN;
  float* wn  = ws + off; off += (size_t)NROWS_TOT;
  float* bufG = ws + off; off += (size_t)NB * CHK * DH;  // act_q / g / dgba*l0
  float* bufH = ws + off; off += (size_t)NB * CHK * DH;  // hb / dhbm*l2
  float* bufD = ws + off; off += (size_t)NB * CHK * DH;  // dh / hidden*l1

  k_init<<<NROWS_TOT, 64, 0, stream>>>(w0, w1, w2, w0m, w1m, w2m, w0c, w1c, w2c, wn);

  for (int ch = 0; ch < NCHK; ++ch) {
    // out_chunk = swiglu(q_chunk; wc)  — uses weights BEFORE this chunk's update
    k_gh<0><<<dim3(DH/64, CHK/64, NB), 256, 0, stream>>>(q, w0c, w2c, bufG, nullptr, ch);
    k_out  <<<dim3(DOUT/64, CHK/64, NB), 256, 0, stream>>>(bufG, w1c, out, ch);
    if (ch == NCHK - 1) break;

    // forward on keys
    k_gh<1><<<dim3(DH/64, CHK/64, NB), 256, 0, stream>>>(k, w0c, w2c, bufG, bufH, ch);
    // dh = v @ w1
    k_dh   <<<dim3(DH/64, CHK/64, NB), 256, 0, stream>>>(v, w1c, bufD, ch);
    // elementwise backprop (+ lr scaling), in-place
    k_bwd  <<<(NB * CHK * DH) / 4 / 256, 256, 0, stream>>>(bufG, bufH, bufD, lr0, lr1, lr2, ch);
    // w0m += dgba_s^T @ k_chunk ; w2m += dhbm_s^T @ k_chunk
    k_dw<true><<<dim3(DIN/64, DH/64, NB), 256, 0, stream>>>(
        bufG, bufH, k + (size_t)ch * CHK * DIN, w0m, w2m,
        DH, (size_t)CHK * DH, DIN, (size_t)LSEQ * DIN, DH, DIN);
    // w1m += v_chunk^T @ (hidden*l1)
    k_dw<false><<<dim3(DH/64, DOUT/64, NB), 256, 0, stream>>>(
        v + (size_t)ch * CHK * DOUT, nullptr, bufD, w1m, nullptr,
        DOUT, (size_t)LSEQ * DOUT, DH, (size_t)CHK * DH, DOUT, DH);
    // renormalize all three weights
    k_renorm<<<NROWS_TOT, 64, 0, stream>>>(w0m, w1m, w2m, w0c, w1c, w2c, wn);
  }
}

// Round 3
// 2194.068 us; speedup vs baseline: 1.2885x; 1.2885x over previous
//
#include <hip/hip_runtime.h>
#include <cmath>

typedef unsigned short u16;
typedef __attribute__((ext_vector_type(8))) short short8;
typedef __attribute__((ext_vector_type(4))) float f32x4;

#define DEVINL __device__ __forceinline__

// Problem constants
constexpr int NB   = 8;
constexpr int LSEQ = 8192;
constexpr int DIN  = 256;
constexpr int DH   = 512;
constexpr int DOUT = 256;
constexpr int CHK  = 1024;
constexpr int NCHK = LSEQ / CHK;

// ---------------------------------------------------------------------------
// bf16 limb splits (truncation; residual captured exactly by next limb)
// ---------------------------------------------------------------------------
DEVINL void split2f(float v, u16& h, u16& l) {
  unsigned u = __builtin_bit_cast(unsigned, v);
  u16 hh = (u16)(u >> 16);
  float fh = __builtin_bit_cast(float, (unsigned)hh << 16);
  float r = v - fh;
  h = hh;
  l = (u16)(__builtin_bit_cast(unsigned, r) >> 16);
}
DEVINL void split3f(float v, u16& h, u16& m, u16& l) {
  unsigned u = __builtin_bit_cast(unsigned, v);
  u16 hh = (u16)(u >> 16);
  float fh = __builtin_bit_cast(float, (unsigned)hh << 16);
  float r1 = v - fh;
  u16 mm = (u16)(__builtin_bit_cast(unsigned, r1) >> 16);
  float fm = __builtin_bit_cast(float, (unsigned)mm << 16);
  float r2 = r1 - fm;
  h = hh; m = mm;
  l = (u16)(__builtin_bit_cast(unsigned, r2) >> 16);
}

// async global->LDS, 16B per lane, wave-uniform LDS base
DEVINL void gl16(const u16* g, u16* l) {
  __builtin_amdgcn_global_load_lds(
      (const __attribute__((address_space(1))) unsigned int*)g,
      (__attribute__((address_space(3))) unsigned int*)l,
      16, 0, 0);
}

template<int BK> DEVINL int swz(int r) { return (BK == 64) ? (r & 7) : ((r >> 1) & 3); }

// ---------------------------------------------------------------------------
// Generic NT multi-limb MFMA GEMM.
//   C[m][n] (+)= sum_k A[m][k] * B[n][k]      (operands [rows][K], bf16 limbs)
// Limbs of A at A + s*sLA (same for D), limbs of B at B + s*sLB (same for E).
// DUAL: 0 = single, 1 = dual-A (A,D share B), 2 = dual-B (B,E share A)
// EPI : 0 = store f32 out0          1 = store f32 out0,out1 (dual)
//       2 = out0 += acc             3 = out0 += acc0, out1 += acc1 (dual)
//       4 = dual-B swiglu: act = silu(acc0)*acc1 -> split2 -> oh, ol
// ---------------------------------------------------------------------------
template<int BM, int BN, int BK, int NS, int DUAL, int EPI>
__global__ __launch_bounds__(256)
void k_gemm(const u16* A, const u16* D, const u16* B, const u16* E,
            long sLA, long sLB,
            float* __restrict__ out0, float* __restrict__ out1,
            u16* __restrict__ oh, u16* __restrict__ ol,
            int K, int ldo, long sAb, long sBb, long sOb)
{
  constexpr int NA  = (DUAL == 1) ? 2 : 1;
  constexpr int NB_ = (DUAL == 2) ? 2 : 1;
  constexpr int NDUP = DUAL ? 2 : 1;
  constexpr int SLOTS = BK / 8;        // 16B slots per LDS row
  constexpr int RPC = 64 / SLOTS;      // rows per 1KB staging chunk
  constexpr int TBA = BM * BK;         // u16 elements per A tile
  constexpr int TBB = BN * BK;
  constexpr int NTA = NA * NS, NTB = NB_ * NS;
  constexpr int CPA = BM / RPC, CPB = BN / RPC;
  constexpr int NCHUNK = NTA * CPA + NTB * CPB;
  constexpr int WM = BM / 2, WN = BN / 2, FM = WM / 16, FN = WN / 16;
  constexpr int NPROD = (NS == 2) ? 3 : 6;
  constexpr int KSTEPS = BK / 32;

  static constexpr int PSA[6] = {0, 0, 1, 0, 1, 2};
  static constexpr int PSB[6] = {0, 1, 0, 2, 1, 0};

  __shared__ alignas(16) u16 lds[(NTA * BM + NTB * BN) * BK];

  const int b  = blockIdx.z;
  const int m0 = blockIdx.y * BM;
  const int n0 = blockIdx.x * BN;
  const int tid = threadIdx.x, wid = tid >> 6, ln = tid & 63;
  const int wm = wid >> 1, wn = wid & 1;

  const u16* Ap = A + (size_t)b * sAb + (size_t)m0 * K;
  const u16* Dp = (DUAL == 1) ? (D + (size_t)b * sAb + (size_t)m0 * K) : nullptr;
  const u16* Bp = B + (size_t)b * sBb + (size_t)n0 * K;
  const u16* Ep = (DUAL == 2) ? (E + (size_t)b * sBb + (size_t)n0 * K) : nullptr;

  f32x4 acc[NDUP][FM][FN];
#pragma unroll
  for (int d = 0; d < NDUP; ++d)
#pragma unroll
    for (int i = 0; i < FM; ++i)
#pragma unroll
      for (int j = 0; j < FN; ++j)
        acc[d][i][j] = (f32x4){0.f, 0.f, 0.f, 0.f};

  const int crow = ln / SLOTS;
  const int cslot = ln % SLOTS;

#pragma unroll 1
  for (int k0 = 0; k0 < K; k0 += BK) {
    // ---- stage all tiles (1KB per wave-instruction, linear LDS dest) ----
    for (int c = wid; c < NCHUNK; c += 4) {
      const u16* g;
      u16* ldst;
      if (c < NTA * CPA) {
        const int tile = c / CPA, rb = c % CPA;
        const int da = tile / NS, s = tile % NS;
        const int r = rb * RPC + crow;
        const int kb = cslot ^ swz<BK>(r);
        const u16* base = (NA == 2 && da == 1) ? Dp : Ap;
        g = base + (size_t)s * sLA + (size_t)r * K + k0 + kb * 8;
        ldst = lds + tile * TBA + rb * (RPC * BK);
      } else {
        const int c2 = c - NTA * CPA;
        const int tile = c2 / CPB, rb = c2 % CPB;
        const int db = tile / NS, s = tile % NS;
        const int r = rb * RPC + crow;
        const int kb = cslot ^ swz<BK>(r);
        const u16* base = (NB_ == 2 && db == 1) ? Ep : Bp;
        g = base + (size_t)s * sLB + (size_t)r * K + k0 + kb * 8;
        ldst = lds + NTA * TBA + tile * TBB + rb * (RPC * BK);
      }
      gl16(g, ldst);
    }
    __syncthreads();

    // ---- compute ----
    const int ro = ln & 15, ko = ln >> 4;
#pragma unroll
    for (int ks = 0; ks < KSTEPS; ++ks) {
      short8 af[NA][NS][FM], bfr[NB_][NS][FN];
#pragma unroll
      for (int da = 0; da < NA; ++da)
#pragma unroll
        for (int s = 0; s < NS; ++s)
#pragma unroll
          for (int im = 0; im < FM; ++im) {
            const int row = wm * WM + im * 16 + ro;
            const int kb = ks * 4 + ko;
            const int phys = kb ^ swz<BK>(row);
            af[da][s][im] = *(const short8*)(lds + (da * NS + s) * TBA + row * BK + phys * 8);
          }
#pragma unroll
      for (int db = 0; db < NB_; ++db)
#pragma unroll
        for (int s = 0; s < NS; ++s)
#pragma unroll
          for (int in = 0; in < FN; ++in) {
            const int row = wn * WN + in * 16 + ro;
            const int kb = ks * 4 + ko;
            const int phys = kb ^ swz<BK>(row);
            bfr[db][s][in] = *(const short8*)(lds + NTA * TBA + (db * NS + s) * TBB + row * BK + phys * 8);
          }
#pragma unroll
      for (int p = 0; p < NPROD; ++p) {
        const int sa = PSA[p], sb = PSB[p];
#pragma unroll
        for (int d = 0; d < NDUP; ++d) {
          const int da = (DUAL == 1) ? d : 0;
          const int db = (DUAL == 2) ? d : 0;
#pragma unroll
          for (int im = 0; im < FM; ++im)
#pragma unroll
            for (int in = 0; in < FN; ++in)
              acc[d][im][in] = __builtin_amdgcn_mfma_f32_16x16x32_bf16(
                  af[da][sa][im], bfr[db][sb][in], acc[d][im][in], 0, 0, 0);
        }
      }
    }
    __syncthreads();
  }

  // ---- epilogue (C/D: col = lane&15, row = (lane>>4)*4 + reg) ----
#pragma unroll
  for (int im = 0; im < FM; ++im)
#pragma unroll
    for (int in = 0; in < FN; ++in)
#pragma unroll
      for (int r = 0; r < 4; ++r) {
        const int row = m0 + wm * WM + im * 16 + (ln >> 4) * 4 + r;
        const int col = n0 + wn * WN + in * 16 + (ln & 15);
        const size_t o = (size_t)b * sOb + (size_t)row * ldo + col;
        if (EPI == 0) {
          out0[o] = acc[0][im][in][r];
        } else if (EPI == 1) {
          out0[o] = acc[0][im][in][r];
          out1[o] = acc[1][im][in][r];
        } else if (EPI == 2) {
          out0[o] += acc[0][im][in][r];
        } else if (EPI == 3) {
          out0[o] += acc[0][im][in][r];
          out1[o] += acc[1][im][in][r];
        } else {
          const float g = acc[0][im][in][r];
          const float h = acc[1][im][in][r];
          const float s = 1.f / (1.f + expf(-g));
          const float a = g * s * h;
          u16 hh, ll;
          split2f(a, hh, ll);
          oh[o] = hh;
          ol[o] = ll;
        }
      }
}

// ---------------------------------------------------------------------------
// Elementwise SwiGLU backprop in transposed space [B][DH][C], lr-scaled,
// 3-limb split outputs for the dw GEMMs.
// ---------------------------------------------------------------------------
__global__ __launch_bounds__(256)
void k_bwd(const float* __restrict__ gT, const float* __restrict__ hT,
           const float* __restrict__ dT,
           const float* __restrict__ lr0, const float* __restrict__ lr1,
           const float* __restrict__ lr2,
           u16* __restrict__ gb0, u16* __restrict__ gb1, u16* __restrict__ gb2,
           u16* __restrict__ hb0, u16* __restrict__ hb1, u16* __restrict__ hb2,
           u16* __restrict__ hd0, u16* __restrict__ hd1, u16* __restrict__ hd2,
           int ch)
{
  const size_t i4 = (size_t)blockIdx.x * 256 + threadIdx.x;
  const size_t base = i4 * 4;
  const int c = (int)(base & 1023);
  const size_t bh = base >> 10;
  const int b = (int)(bh >> 9);
  const size_t li = (size_t)b * LSEQ + (size_t)ch * CHK + c;

  const float4 g4 = *(const float4*)&gT[base];
  const float4 h4 = *(const float4*)&hT[base];
  const float4 d4 = *(const float4*)&dT[base];
  const float4 L0 = *(const float4*)&lr0[li];
  const float4 L1 = *(const float4*)&lr1[li];
  const float4 L2 = *(const float4*)&lr2[li];
  const float gv[4] = {g4.x, g4.y, g4.z, g4.w};
  const float hv[4] = {h4.x, h4.y, h4.z, h4.w};
  const float dv[4] = {d4.x, d4.y, d4.z, d4.w};
  const float l0v[4] = {L0.x, L0.y, L0.z, L0.w};
  const float l1v[4] = {L1.x, L1.y, L1.z, L1.w};
  const float l2v[4] = {L2.x, L2.y, L2.z, L2.w};

  ushort4 og0, og1, og2, oh0, oh1, oh2, od0, od1, od2;
  u16* pg0 = &og0.x; u16* pg1 = &og1.x; u16* pg2 = &og2.x;
  u16* ph0 = &oh0.x; u16* ph1 = &oh1.x; u16* ph2 = &oh2.x;
  u16* pd0 = &od0.x; u16* pd1 = &od1.x; u16* pd2 = &od2.x;
#pragma unroll
  for (int t = 0; t < 4; ++t) {
    const float g = gv[t];
    const float sig = 1.f / (1.f + expf(-g));
    const float sg = g * sig;
    const float hidden = sg * hv[t];
    const float dhbm = dv[t] * sg;
    const float dgrad = dv[t] * hv[t];
    const float dgba = dgrad * sig * (1.f + g * (1.f - sig));
    split3f(dgba * l0v[t], pg0[t], pg1[t], pg2[t]);
    split3f(dhbm * l2v[t], ph0[t], ph1[t], ph2[t]);
    split3f(hidden * l1v[t], pd0[t], pd1[t], pd2[t]);
  }
  *(ushort4*)&gb0[base] = og0; *(ushort4*)&gb1[base] = og1; *(ushort4*)&gb2[base] = og2;
  *(ushort4*)&hb0[base] = oh0; *(ushort4*)&hb1[base] = oh1; *(ushort4*)&hb2[base] = oh2;
  *(ushort4*)&hd0[base] = od0; *(ushort4*)&hd1[base] = od1; *(ushort4*)&hd2[base] = od2;
}

// ---------------------------------------------------------------------------
// q/k/v chunk splits (q: 2 limbs, k/v: 3 limbs); chunk buffers [B][CHK][256]
// ---------------------------------------------------------------------------
__global__ __launch_bounds__(256)
void k_split3(const float* __restrict__ q, const float* __restrict__ k,
              const float* __restrict__ v,
              u16* __restrict__ q0, u16* __restrict__ q1,
              u16* __restrict__ k0s, u16* __restrict__ k1s, u16* __restrict__ k2s,
              u16* __restrict__ v0s, u16* __restrict__ v1s, u16* __restrict__ v2s,
              int ch)
{
  const int sec = blockIdx.y;
  const size_t base = ((size_t)blockIdx.x * 256 + threadIdx.x) * 4;  // [0, 2M)
  const int b = (int)(base >> 18);
  const size_t rem = base & 0x3FFFF;
  const size_t soff = (size_t)b * (LSEQ * 256) + (size_t)ch * (CHK * 256) + rem;

  const float* src = (sec == 0) ? q : (sec == 1) ? k : v;
  const float4 x4 = *(const float4*)&src[soff];
  const float xv[4] = {x4.x, x4.y, x4.z, x4.w};

  if (sec == 0) {
    ushort4 a, bq;
    u16* pa = &a.x; u16* pb = &bq.x;
#pragma unroll
    for (int t = 0; t < 4; ++t) split2f(xv[t], pa[t], pb[t]);
    *(ushort4*)&q0[base] = a;
    *(ushort4*)&q1[base] = bq;
  } else {
    ushort4 a, bq, cq;
    u16* pa = &a.x; u16* pb = &bq.x; u16* pc = &cq.x;
#pragma unroll
    for (int t = 0; t < 4; ++t) split3f(xv[t], pa[t], pb[t], pc[t]);
    u16* d0 = (sec == 1) ? k0s : v0s;
    u16* d1 = (sec == 1) ? k1s : v1s;
    u16* d2 = (sec == 1) ? k2s : v2s;
    *(ushort4*)&d0[base] = a;
    *(ushort4*)&d1[base] = bq;
    *(ushort4*)&d2[base] = cq;
  }
}

// ---------------------------------------------------------------------------
// Tiled transpose + 3-limb split: src [B][LSEQ][256] chunk -> dst [B][256][CHK]
// ---------------------------------------------------------------------------
__global__ __launch_bounds__(256)
void k_trans(const float* __restrict__ src, u16* __restrict__ d0,
             u16* __restrict__ d1, u16* __restrict__ d2, int ch)
{
  __shared__ float T[64][65];
  const int b = blockIdx.z;
  const int ct = blockIdx.x;  // c tile (0..15)
  const int dt = blockIdx.y;  // d tile (0..3)
  const int tid = threadIdx.x;
  const float* S = src + ((size_t)b * LSEQ + (size_t)ch * CHK + ct * 64) * 256 + dt * 64;

#pragma unroll
  for (int qq = 0; qq < 4; ++qq) {
    const int flat = qq * 256 + tid;
    const int r = flat >> 4;           // c row
    const int cq = (flat & 15) * 4;    // d col
    const float4 v4 = *(const float4*)&S[(size_t)r * 256 + cq];
    T[r][cq + 0] = v4.x; T[r][cq + 1] = v4.y; T[r][cq + 2] = v4.z; T[r][cq + 3] = v4.w;
  }
  __syncthreads();

  u16* D0 = d0 + (size_t)b * (256 * CHK) + (size_t)(dt * 64) * CHK + ct * 64;
  u16* D1 = d1 + (size_t)b * (256 * CHK) + (size_t)(dt * 64) * CHK + ct * 64;
  u16* D2 = d2 + (size_t)b * (256 * CHK) + (size_t)(dt * 64) * CHK + ct * 64;
#pragma unroll
  for (int qq = 0; qq < 4; ++qq) {
    const int flat = qq * 256 + tid;
    const int rr = flat >> 4;          // d row
    const int cc = (flat & 15) * 4;    // c col
    ushort4 a, bq, cq4;
    u16* pa = &a.x; u16* pb = &bq.x; u16* pc = &cq4.x;
#pragma unroll
    for (int i = 0; i < 4; ++i) split3f(T[cc + i][rr], pa[i], pb[i], pc[i]);
    const size_t o = (size_t)rr * CHK + cc;
    *(ushort4*)&D0[o] = a;
    *(ushort4*)&D1[o] = bq;
    *(ushort4*)&D2[o] = cq4;
  }
}

// ---------------------------------------------------------------------------
// w1 transpose + scale + 3-limb split: wm1 [B][256][512] -> w1T [B][512][256]
// ---------------------------------------------------------------------------
__global__ __launch_bounds__(256)
void k_w1t(const float* __restrict__ wm1, const float* __restrict__ scales,
           u16* __restrict__ d0, u16* __restrict__ d1, u16* __restrict__ d2)
{
  __shared__ float T[64][65];
  const int b = blockIdx.z;
  const int ot = blockIdx.x;  // o tile (0..3)
  const int ht = blockIdx.y;  // h tile (0..7)
  const int tid = threadIdx.x;
  const float* S = wm1 + (size_t)b * (256 * 512) + (size_t)(ot * 64) * 512 + ht * 64;
  const float* sc = scales + 4096 + b * 256 + ot * 64;

#pragma unroll
  for (int qq = 0; qq < 4; ++qq) {
    const int flat = qq * 256 + tid;
    const int r = flat >> 4;
    const int cq = (flat & 15) * 4;
    const float s = sc[r];
    const float4 v4 = *(const float4*)&S[(size_t)r * 512 + cq];
    T[r][cq + 0] = v4.x * s; T[r][cq + 1] = v4.y * s; T[r][cq + 2] = v4.z * s; T[r][cq + 3] = v4.w * s;
  }
  __syncthreads();

  u16* D0 = d0 + (size_t)b * (512 * 256) + (size_t)(ht * 64) * 256 + ot * 64;
  u16* D1 = d1 + (size_t)b * (512 * 256) + (size_t)(ht * 64) * 256 + ot * 64;
  u16* D2 = d2 + (size_t)b * (512 * 256) + (size_t)(ht * 64) * 256 + ot * 64;
#pragma unroll
  for (int qq = 0; qq < 4; ++qq) {
    const int flat = qq * 256 + tid;
    const int rr = flat >> 4;
    const int cc = (flat & 15) * 4;
    ushort4 a, bq, cq4;
    u16* pa = &a.x; u16* pb = &bq.x; u16* pc = &cq4.x;
#pragma unroll
    for (int i = 0; i < 4; ++i) split3f(T[cc + i][rr], pa[i], pb[i], pc[i]);
    const size_t o = (size_t)rr * 256 + cc;
    *(ushort4*)&D0[o] = a;
    *(ushort4*)&D1[o] = bq;
    *(ushort4*)&D2[o] = cq4;
  }
}

// ---------------------------------------------------------------------------
// Scaled 3-limb split of wm0/wm1/wm2 (row-normalized compute weights)
// ---------------------------------------------------------------------------
__global__ __launch_bounds__(256)
void k_wsplit(const float* __restrict__ wm0, const float* __restrict__ wm1,
              const float* __restrict__ wm2, const float* __restrict__ scales,
              u16* __restrict__ a00, u16* __restrict__ a01, u16* __restrict__ a02,
              u16* __restrict__ a10, u16* __restrict__ a11, u16* __restrict__ a12,
              u16* __restrict__ a20, u16* __restrict__ a21, u16* __restrict__ a22)
{
  const size_t e4 = ((size_t)blockIdx.x * 256 + threadIdx.x) * 4;
  const float* src; u16 *d0, *d1, *d2; float s; size_t off;
  if (e4 < 1048576) {
    off = e4; src = wm0; d0 = a00; d1 = a01; d2 = a02;
    s = scales[off >> 8];
  } else if (e4 < 2097152) {
    off = e4 - 1048576; src = wm1; d0 = a10; d1 = a11; d2 = a12;
    s = scales[4096 + (off >> 9)];
  } else {
    off = e4 - 2097152; src = wm2; d0 = a20; d1 = a21; d2 = a22;
    s = scales[6144 + (off >> 8)];
  }
  const float4 v4 = *(const float4*)&src[off];
  const float xv[4] = {v4.x * s, v4.y * s, v4.z * s, v4.w * s};
  ushort4 a, bq, cq;
  u16* pa = &a.x; u16* pb = &bq.x; u16* pc = &cq.x;
#pragma unroll
  for (int t = 0; t < 4; ++t) split3f(xv[t], pa[t], pb[t], pc[t]);
  *(ushort4*)&d0[off] = a;
  *(ushort4*)&d1[off] = bq;
  *(ushort4*)&d2[off] = cq;
}

// ---------------------------------------------------------------------------
// Row norms / scales. Row layout: [0,4096) w0 | [4096,6144) w1 | [6144,10240) w2
// ---------------------------------------------------------------------------
__global__ __launch_bounds__(64)
void k_init(const float* __restrict__ w0, const float* __restrict__ w1,
            const float* __restrict__ w2,
            float* __restrict__ wm0, float* __restrict__ wm1, float* __restrict__ wm2,
            float* __restrict__ wn, float* __restrict__ scales)
{
  const int row = blockIdx.x;
  const float* src; float* dst; int len; int r;
  if (row < 4096)      { r = row;        src = w0; dst = wm0; len = 256; }
  else if (row < 6144) { r = row - 4096; src = w1; dst = wm1; len = 512; }
  else                 { r = row - 6144; src = w2; dst = wm2; len = 256; }
  const float* s = src + (size_t)r * len;
  float* d = dst + (size_t)r * len;
  float ss = 0.f;
  for (int i = threadIdx.x; i < len; i += 64) {
    const float v = s[i];
    d[i] = v;
    ss += v * v;
  }
#pragma unroll
  for (int off = 32; off > 0; off >>= 1) ss += __shfl_down(ss, off);
  if (threadIdx.x == 0) {
    wn[row] = sqrtf(ss);
    scales[row] = 1.f;
  }
}

__global__ __launch_bounds__(64)
void k_scales(const float* __restrict__ wm0, const float* __restrict__ wm1,
              const float* __restrict__ wm2, const float* __restrict__ wn,
              float* __restrict__ scales)
{
  const int row = blockIdx.x;
  const float* src; int len; int r;
  if (row < 4096)      { r = row;        src = wm0; len = 256; }
  else if (row < 6144) { r = row - 4096; src = wm1; len = 512; }
  else                 { r = row - 6144; src = wm2; len = 256; }
  const float* s = src + (size_t)r * len;
  float ss = 0.f;
  for (int i = threadIdx.x; i < len; i += 64) { const float v = s[i]; ss += v * v; }
#pragma unroll
  for (int off = 32; off > 0; off >>= 1) ss += __shfl_down(ss, off);
  if (threadIdx.x == 0) scales[row] = wn[row] / (sqrtf(ss) + 1e-5f);
}

// ---------------------------------------------------------------------------
extern "C" void kernel_launch(void* const* d_in, const int* in_sizes, int n_in,
                              void* d_out, int out_size, void* d_ws, size_t ws_size,
                              hipStream_t stream)
{
  const float* w0  = (const float*)d_in[0];
  const float* w1  = (const float*)d_in[1];
  const float* w2  = (const float*)d_in[2];
  const float* q   = (const float*)d_in[3];
  const float* k   = (const float*)d_in[4];
  const float* v   = (const float*)d_in[5];
  const float* lr0 = (const float*)d_in[6];
  const float* lr1 = (const float*)d_in[7];
  const float* lr2 = (const float*)d_in[8];
  float* out = (float*)d_out;

  float* p = (float*)d_ws;
  size_t o = 0;
  auto AF = [&](size_t n) { float* r = p + o; o += n; return r; };
  auto AH = [&](size_t n) { u16* r = (u16*)(p + o); o += n / 2; return r; };

  constexpr long WL = 1048576;   // weight limb stride (u16)
  constexpr long XL = 2097152;   // input-chunk limb stride (u16)
  constexpr long HL = 4194304;   // hidden-sized limb stride (u16)

  float* wm0 = AF(1048576);
  float* wm1 = AF(1048576);
  float* wm2 = AF(1048576);
  float* wn = AF(10240);
  float* scales = AF(10240);
  float* gT  = AF(4194304);
  float* hT  = AF(4194304);
  float* dhT = AF(4194304);
  u16* w0s  = AH(3 * WL);
  u16* w2s  = AH(3 * WL);
  u16* w1s  = AH(3 * WL);
  u16* w1Ts = AH(3 * WL);
  u16* qs   = AH(2 * XL);
  u16* ks3  = AH(3 * XL);
  u16* vs3  = AH(3 * XL);
  u16* gbs  = AH(3 * HL);
  u16* hbs  = AH(3 * HL);
  u16* hds  = AH(3 * HL);
  // stream-ordered aliases (producers launch strictly after consumers drain):
  u16* kTs  = ks3;   // k^T limbs overwrite k-split limbs after keys GEMM
  u16* vTs  = vs3;   // v^T limbs overwrite v-split limbs after dh GEMM
  u16* acts = gbs;   // act limbs (2) use gbs limbs 0,1 (dead until k_bwd)

  // init: wm = w, wn = row norms, scales = 1
  k_init<<<10240, 64, 0, stream>>>(w0, w1, w2, wm0, wm1, wm2, wn, scales);
  k_wsplit<<<3072, 256, 0, stream>>>(wm0, wm1, wm2, scales,
      w0s, w0s + WL, w0s + 2 * WL, w1s, w1s + WL, w1s + 2 * WL,
      w2s, w2s + WL, w2s + 2 * WL);
  k_w1t<<<dim3(4, 8, NB), 256, 0, stream>>>(wm1, scales,
      w1Ts, w1Ts + WL, w1Ts + 2 * WL);

  for (int ch = 0; ch < NCHK; ++ch) {
    // input chunk splits
    k_split3<<<dim3(2048, 3), 256, 0, stream>>>(q, k, v,
        qs, qs + XL, ks3, ks3 + XL, ks3 + 2 * XL, vs3, vs3 + XL, vs3 + 2 * XL, ch);

    // apply: act = silu(q w0^T) * (q w2^T)   [dual-B, 2-limb, swiglu epilogue]
    k_gemm<128, 64, 64, 2, 2, 4><<<dim3(8, 8, NB), 256, 0, stream>>>(
        qs, nullptr, w0s, w2s, XL, WL,
        nullptr, nullptr, acts, acts + HL,
        256, DH, 262144, 131072, (long)CHK * DH);
    // out = act w1^T
    k_gemm<128, 64, 64, 2, 0, 0><<<dim3(4, 8, NB), 256, 0, stream>>>(
        acts, nullptr, w1s, nullptr, HL, WL,
        out + (size_t)ch * CHK * DOUT, nullptr, nullptr, nullptr,
        512, DOUT, (long)CHK * DH, 131072, (long)LSEQ * DOUT);

    if (ch == NCHK - 1) break;

    // keys forward (transposed): gT = w0 k^T, hT = w2 k^T  [dual-A, 3-limb]
    k_gemm<64, 128, 32, 3, 1, 1><<<dim3(8, 8, NB), 256, 0, stream>>>(
        w0s, w2s, ks3, nullptr, WL, XL,
        gT, hT, nullptr, nullptr,
        256, CHK, 131072, 262144, (long)DH * CHK);
    // dhT = w1T v^T  [3-limb]
    k_gemm<64, 128, 32, 3, 0, 0><<<dim3(8, 8, NB), 256, 0, stream>>>(
        w1Ts, nullptr, vs3, nullptr, WL, XL,
        dhT, nullptr, nullptr, nullptr,
        256, CHK, 131072, 262144, (long)DH * CHK);

    // elementwise backprop + lr scale + 3-limb split (transposed space)
    k_bwd<<<4096, 256, 0, stream>>>(gT, hT, dhT, lr0, lr1, lr2,
        gbs, gbs + HL, gbs + 2 * HL, hbs, hbs + HL, hbs + 2 * HL,
        hds, hds + HL, hds + 2 * HL, ch);

    // kT, vT (3-limb, transposed chunk) — alias writes AFTER consumers drained
    k_trans<<<dim3(16, 4, NB), 256, 0, stream>>>(k, kTs, kTs + XL, kTs + 2 * XL, ch);
    k_trans<<<dim3(16, 4, NB), 256, 0, stream>>>(v, vTs, vTs + XL, vTs + 2 * XL, ch);

    // dw0 += gbT kT^T ; dw2 += hbT kT^T  [dual-A, 3-limb]
    k_gemm<64, 64, 32, 3, 1, 3><<<dim3(4, 8, NB), 256, 0, stream>>>(
        gbs, hbs, kTs, nullptr, HL, XL,
        wm0, wm2, nullptr, nullptr,
        1024, DIN, (long)DH * CHK, (long)DIN * CHK, (long)DH * DIN);
    // dw1 += vT hidT^T  [3-limb]
    k_gemm<64, 64, 32, 3, 0, 2><<<dim3(8, 4, NB), 256, 0, stream>>>(
        vTs, nullptr, hds, nullptr, XL, HL,
        wm1, nullptr, nullptr, nullptr,
        1024, DH, (long)DOUT * CHK, (long)DH * CHK, (long)DOUT * DH);

    // renorm scales + refresh bf16 weight limbs
    k_scales<<<10240, 64, 0, stream>>>(wm0, wm1, wm2, wn, scales);
    k_wsplit<<<3072, 256, 0, stream>>>(wm0, wm1, wm2, scales,
        w0s, w0s + WL, w0s + 2 * WL, w1s, w1s + WL, w1s + 2 * WL,
        w2s, w2s + WL, w2s + 2 * WL);
    k_w1t<<<dim3(4, 8, NB), 256, 0, stream>>>(wm1, scales,
        w1Ts, w1Ts + WL, w1Ts + 2 * WL);
  }
}

// Round 5
// 1833.045 us; speedup vs baseline: 1.5423x; 1.1970x over previous
//
#include <hip/hip_runtime.h>
#include <cmath>

typedef unsigned short u16;
typedef __attribute__((ext_vector_type(8))) short short8;
typedef __attribute__((ext_vector_type(4))) float f32x4;

#define DEVINL __device__ __forceinline__

// Problem constants
constexpr int NB   = 8;
constexpr int LSEQ = 8192;
constexpr int DIN  = 256;
constexpr int DH   = 512;
constexpr int DOUT = 256;
constexpr int CHK  = 1024;
constexpr int NCHK = LSEQ / CHK;

// ---------------------------------------------------------------------------
// bf16 limb splits (truncation; residual captured exactly by next limb)
// ---------------------------------------------------------------------------
DEVINL void split2f(float v, u16& h, u16& l) {
  unsigned u = __builtin_bit_cast(unsigned, v);
  u16 hh = (u16)(u >> 16);
  float fh = __builtin_bit_cast(float, (unsigned)hh << 16);
  float r = v - fh;
  h = hh;
  l = (u16)(__builtin_bit_cast(unsigned, r) >> 16);
}
DEVINL void split3f(float v, u16& h, u16& m, u16& l) {
  unsigned u = __builtin_bit_cast(unsigned, v);
  u16 hh = (u16)(u >> 16);
  float fh = __builtin_bit_cast(float, (unsigned)hh << 16);
  float r1 = v - fh;
  u16 mm = (u16)(__builtin_bit_cast(unsigned, r1) >> 16);
  float fm = __builtin_bit_cast(float, (unsigned)mm << 16);
  float r2 = r1 - fm;
  h = hh; m = mm;
  l = (u16)(__builtin_bit_cast(unsigned, r2) >> 16);
}

// async global->LDS, 16B per lane, wave-uniform LDS base
DEVINL void gl16(const u16* g, u16* l) {
  __builtin_amdgcn_global_load_lds(
      (const __attribute__((address_space(1))) unsigned int*)g,
      (__attribute__((address_space(3))) unsigned int*)l,
      16, 0, 0);
}

template<int BK> DEVINL int swz(int r) { return (BK == 64) ? (r & 7) : ((r >> 1) & 3); }

// ---------------------------------------------------------------------------
// Generic NT multi-limb MFMA GEMM, flat grid with XCD-aware mapping:
//   fid = blockIdx.x; batch = fid & 7  (all blocks of a batch -> one XCD's L2)
//   C[m][n] (+)= sum_k A[m][k] * B[n][k]      (operands [rows][K], bf16 limbs)
// DUAL: 0 single, 1 dual-A (A,D share B), 2 dual-B (B,E share A)
// EPI : 0 store f32 out0; 1 store out0,out1 (dual); 2 out0+=; 3 dual +=;
//       4 dual-B swiglu: act = silu(acc0)*acc1 -> split2 -> oh, ol
// MERGE=1: grid also covers a second single-A job (A2*B2 -> out2, same BM/BN/BK/K)
// ---------------------------------------------------------------------------
template<int BM, int BN, int BK, int NS, int DUAL, int EPI, int MERGE>
__global__ __launch_bounds__(256)
void k_gemm(const u16* A, const u16* D, const u16* B, const u16* E,
            long sLA, long sLB,
            float* __restrict__ out0, float* __restrict__ out1,
            u16* __restrict__ oh, u16* __restrict__ ol,
            int K, int ldo, long sAb, long sBb, long sOb,
            int NTX, int NTY,
            const u16* A2, const u16* B2, long sLA2, long sLB2,
            float* __restrict__ out2, int ldo2,
            long sA2b, long sB2b, long sO2b, int NTX2)
{
  constexpr int NA  = (DUAL == 1) ? 2 : 1;
  constexpr int NB_ = (DUAL == 2) ? 2 : 1;
  constexpr int NDUP = DUAL ? 2 : 1;
  constexpr int SLOTS = BK / 8;        // 16B slots per LDS row
  constexpr int RPC = 64 / SLOTS;      // rows per 1KB staging chunk
  constexpr int TBA = BM * BK;         // u16 elements per A tile
  constexpr int TBB = BN * BK;
  constexpr int NTA = NA * NS, NTB = NB_ * NS;
  constexpr int CPA = BM / RPC, CPB = BN / RPC;
  constexpr int NCHUNK = NTA * CPA + NTB * CPB;
  constexpr int WM = BM / 2, WN = BN / 2, FM = WM / 16, FN = WN / 16;
  constexpr int NPROD = (NS == 2) ? 3 : 6;
  constexpr int KSTEPS = BK / 32;

  static constexpr int PSA[6] = {0, 0, 1, 0, 1, 2};
  static constexpr int PSB[6] = {0, 1, 0, 2, 1, 0};

  __shared__ alignas(16) u16 lds[(NTA * BM + NTB * BN) * BK];

  // XCD-aware decode
  const int fid = blockIdx.x;
  const int b = fid & 7;
  int t = fid >> 3;
  int job = 0;
  if (MERGE) {
    if (t >= NTY * NTX) { job = 1; t -= NTY * NTX; }
  }
  const int ntx = (MERGE && job) ? NTX2 : NTX;
  const int my = t / ntx, nx = t % ntx;
  const int m0 = my * BM;
  const int n0 = nx * BN;

  const int tid = threadIdx.x, wid = tid >> 6, ln = tid & 63;
  const int wm = wid >> 1, wn = wid & 1;

  const u16* Ap; const u16* Dp = nullptr; const u16* Bp; const u16* Ep = nullptr;
  long eLA, eLB; int eldo; long eOb;
  if (MERGE && job) {
    Ap = A2 + (size_t)b * sA2b + (size_t)m0 * K;
    Bp = B2 + (size_t)b * sB2b + (size_t)n0 * K;
    eLA = sLA2; eLB = sLB2; eldo = ldo2; eOb = sO2b;
  } else {
    Ap = A + (size_t)b * sAb + (size_t)m0 * K;
    if (DUAL == 1) Dp = D + (size_t)b * sAb + (size_t)m0 * K;
    Bp = B + (size_t)b * sBb + (size_t)n0 * K;
    if (DUAL == 2) Ep = E + (size_t)b * sBb + (size_t)n0 * K;
    eLA = sLA; eLB = sLB; eldo = ldo; eOb = sOb;
  }

  f32x4 acc[NDUP][FM][FN];
#pragma unroll
  for (int d = 0; d < NDUP; ++d)
#pragma unroll
    for (int i = 0; i < FM; ++i)
#pragma unroll
      for (int j = 0; j < FN; ++j)
        acc[d][i][j] = (f32x4){0.f, 0.f, 0.f, 0.f};

  const int crow = ln / SLOTS;
  const int cslot = ln % SLOTS;

#pragma unroll 1
  for (int k0 = 0; k0 < K; k0 += BK) {
    // ---- stage tiles (1KB per wave-instruction, linear LDS dest) ----
    for (int c = wid; c < NCHUNK; c += 4) {
      const u16* g;
      u16* ldst;
      if (c < NTA * CPA) {
        const int tile = c / CPA, rb = c % CPA;
        const int da = tile / NS, s = tile % NS;
        if (MERGE && job && da == 1) continue;   // job1 is single-A
        const int r = rb * RPC + crow;
        const int kb = cslot ^ swz<BK>(r);
        const u16* base = (NA == 2 && da == 1) ? Dp : Ap;
        g = base + (size_t)s * eLA + (size_t)r * K + k0 + kb * 8;
        ldst = lds + tile * TBA + rb * (RPC * BK);
      } else {
        const int c2 = c - NTA * CPA;
        const int tile = c2 / CPB, rb = c2 % CPB;
        const int db = tile / NS, s = tile % NS;
        const int r = rb * RPC + crow;
        const int kb = cslot ^ swz<BK>(r);
        const u16* base = (NB_ == 2 && db == 1) ? Ep : Bp;
        g = base + (size_t)s * eLB + (size_t)r * K + k0 + kb * 8;
        ldst = lds + NTA * TBA + tile * TBB + rb * (RPC * BK);
      }
      gl16(g, ldst);
    }
    __syncthreads();

    // ---- compute ----
    const int ro = ln & 15, ko = ln >> 4;
#pragma unroll
    for (int ks = 0; ks < KSTEPS; ++ks) {
      short8 af[NA][NS][FM], bfr[NB_][NS][FN];
#pragma unroll
      for (int da = 0; da < NA; ++da) {
        if (MERGE && job && da == 1) continue;
#pragma unroll
        for (int s = 0; s < NS; ++s)
#pragma unroll
          for (int im = 0; im < FM; ++im) {
            const int row = wm * WM + im * 16 + ro;
            const int kb = ks * 4 + ko;
            const int phys = kb ^ swz<BK>(row);
            af[da][s][im] = *(const short8*)(lds + (da * NS + s) * TBA + row * BK + phys * 8);
          }
      }
#pragma unroll
      for (int db = 0; db < NB_; ++db)
#pragma unroll
        for (int s = 0; s < NS; ++s)
#pragma unroll
          for (int in = 0; in < FN; ++in) {
            const int row = wn * WN + in * 16 + ro;
            const int kb = ks * 4 + ko;
            const int phys = kb ^ swz<BK>(row);
            bfr[db][s][in] = *(const short8*)(lds + NTA * TBA + (db * NS + s) * TBB + row * BK + phys * 8);
          }
#pragma unroll
      for (int p = 0; p < NPROD; ++p) {
        const int sa = PSA[p], sb = PSB[p];
#pragma unroll
        for (int d = 0; d < NDUP; ++d) {
          if (MERGE && job && d == 1) continue;
          const int da = (DUAL == 1) ? d : 0;
          const int db = (DUAL == 2) ? d : 0;
#pragma unroll
          for (int im = 0; im < FM; ++im)
#pragma unroll
            for (int in = 0; in < FN; ++in)
              acc[d][im][in] = __builtin_amdgcn_mfma_f32_16x16x32_bf16(
                  af[da][sa][im], bfr[db][sb][in], acc[d][im][in], 0, 0, 0);
        }
      }
    }
    __syncthreads();
  }

  // ---- epilogue (C/D: col = lane&15, row = (lane>>4)*4 + reg) ----
#pragma unroll
  for (int im = 0; im < FM; ++im)
#pragma unroll
    for (int in = 0; in < FN; ++in)
#pragma unroll
      for (int r = 0; r < 4; ++r) {
        const int row = m0 + wm * WM + im * 16 + (ln >> 4) * 4 + r;
        const int col = n0 + wn * WN + in * 16 + (ln & 15);
        const size_t o = (size_t)b * eOb + (size_t)row * eldo + col;
        if (MERGE && job) {
          if (EPI == 1) out2[o] = acc[0][im][in][r];
          else          out2[o] += acc[0][im][in][r];
        } else if (EPI == 0) {
          out0[o] = acc[0][im][in][r];
        } else if (EPI == 1) {
          out0[o] = acc[0][im][in][r];
          out1[o] = acc[1][im][in][r];
        } else if (EPI == 2) {
          out0[o] += acc[0][im][in][r];
        } else if (EPI == 3) {
          out0[o] += acc[0][im][in][r];
          out1[o] += acc[1][im][in][r];
        } else {
          const float g = acc[0][im][in][r];
          const float h = acc[1][im][in][r];
          const float s = 1.f / (1.f + expf(-g));
          const float a = g * s * h;
          u16 hh, ll;
          split2f(a, hh, ll);
          oh[o] = hh;
          ol[o] = ll;
        }
      }
}

// ---------------------------------------------------------------------------
// Elementwise SwiGLU backprop in transposed space [B][DH][C], lr-scaled,
// 3-limb split outputs for the dw GEMMs.
// ---------------------------------------------------------------------------
__global__ __launch_bounds__(256)
void k_bwd(const float* __restrict__ gT, const float* __restrict__ hT,
           const float* __restrict__ dT,
           const float* __restrict__ lr0, const float* __restrict__ lr1,
           const float* __restrict__ lr2,
           u16* __restrict__ gb0, u16* __restrict__ gb1, u16* __restrict__ gb2,
           u16* __restrict__ hb0, u16* __restrict__ hb1, u16* __restrict__ hb2,
           u16* __restrict__ hd0, u16* __restrict__ hd1, u16* __restrict__ hd2,
           int ch)
{
  const size_t i4 = (size_t)blockIdx.x * 256 + threadIdx.x;
  const size_t base = i4 * 4;
  const int c = (int)(base & 1023);
  const size_t bh = base >> 10;
  const int b = (int)(bh >> 9);
  const size_t li = (size_t)b * LSEQ + (size_t)ch * CHK + c;

  const float4 g4 = *(const float4*)&gT[base];
  const float4 h4 = *(const float4*)&hT[base];
  const float4 d4 = *(const float4*)&dT[base];
  const float4 L0 = *(const float4*)&lr0[li];
  const float4 L1 = *(const float4*)&lr1[li];
  const float4 L2 = *(const float4*)&lr2[li];
  const float gv[4] = {g4.x, g4.y, g4.z, g4.w};
  const float hv[4] = {h4.x, h4.y, h4.z, h4.w};
  const float dv[4] = {d4.x, d4.y, d4.z, d4.w};
  const float l0v[4] = {L0.x, L0.y, L0.z, L0.w};
  const float l1v[4] = {L1.x, L1.y, L1.z, L1.w};
  const float l2v[4] = {L2.x, L2.y, L2.z, L2.w};

  ushort4 og0, og1, og2, oh0, oh1, oh2, od0, od1, od2;
  u16* pg0 = &og0.x; u16* pg1 = &og1.x; u16* pg2 = &og2.x;
  u16* ph0 = &oh0.x; u16* ph1 = &oh1.x; u16* ph2 = &oh2.x;
  u16* pd0 = &od0.x; u16* pd1 = &od1.x; u16* pd2 = &od2.x;
#pragma unroll
  for (int t = 0; t < 4; ++t) {
    const float g = gv[t];
    const float sig = 1.f / (1.f + expf(-g));
    const float sg = g * sig;
    const float hidden = sg * hv[t];
    const float dhbm = dv[t] * sg;
    const float dgrad = dv[t] * hv[t];
    const float dgba = dgrad * sig * (1.f + g * (1.f - sig));
    split3f(dgba * l0v[t], pg0[t], pg1[t], pg2[t]);
    split3f(dhbm * l2v[t], ph0[t], ph1[t], ph2[t]);
    split3f(hidden * l1v[t], pd0[t], pd1[t], pd2[t]);
  }
  *(ushort4*)&gb0[base] = og0; *(ushort4*)&gb1[base] = og1; *(ushort4*)&gb2[base] = og2;
  *(ushort4*)&hb0[base] = oh0; *(ushort4*)&hb1[base] = oh1; *(ushort4*)&hb2[base] = oh2;
  *(ushort4*)&hd0[base] = od0; *(ushort4*)&hd1[base] = od1; *(ushort4*)&hd2[base] = od2;
}

// ---------------------------------------------------------------------------
// q/k/v chunk splits (q: 2 limbs, k/v: 3 limbs); chunk buffers [B][CHK][256]
// gridDim.y = 3 normally; = 1 on last chunk (q only)
// ---------------------------------------------------------------------------
__global__ __launch_bounds__(256)
void k_split3(const float* __restrict__ q, const float* __restrict__ k,
              const float* __restrict__ v,
              u16* __restrict__ q0, u16* __restrict__ q1,
              u16* __restrict__ k0s, u16* __restrict__ k1s, u16* __restrict__ k2s,
              u16* __restrict__ v0s, u16* __restrict__ v1s, u16* __restrict__ v2s,
              int ch)
{
  const int sec = blockIdx.y;
  const size_t base = ((size_t)blockIdx.x * 256 + threadIdx.x) * 4;  // [0, 2M)
  const int b = (int)(base >> 18);
  const size_t rem = base & 0x3FFFF;
  const size_t soff = (size_t)b * (LSEQ * 256) + (size_t)ch * (CHK * 256) + rem;

  const float* src = (sec == 0) ? q : (sec == 1) ? k : v;
  const float4 x4 = *(const float4*)&src[soff];
  const float xv[4] = {x4.x, x4.y, x4.z, x4.w};

  if (sec == 0) {
    ushort4 a, bq;
    u16* pa = &a.x; u16* pb = &bq.x;
#pragma unroll
    for (int t = 0; t < 4; ++t) split2f(xv[t], pa[t], pb[t]);
    *(ushort4*)&q0[base] = a;
    *(ushort4*)&q1[base] = bq;
  } else {
    ushort4 a, bq, cq;
    u16* pa = &a.x; u16* pb = &bq.x; u16* pc = &cq.x;
#pragma unroll
    for (int t = 0; t < 4; ++t) split3f(xv[t], pa[t], pb[t], pc[t]);
    u16* d0 = (sec == 1) ? k0s : v0s;
    u16* d1 = (sec == 1) ? k1s : v1s;
    u16* d2 = (sec == 1) ? k2s : v2s;
    *(ushort4*)&d0[base] = a;
    *(ushort4*)&d1[base] = bq;
    *(ushort4*)&d2[base] = cq;
  }
}

// ---------------------------------------------------------------------------
// Tiled transpose + 3-limb split: src [B][LSEQ][256] chunk -> dst [B][256][CHK]
// gridDim.z = 16: z&7 = batch, z>>3 = source select (0 -> k->dK, 1 -> v->dV)
// ---------------------------------------------------------------------------
__global__ __launch_bounds__(256)
void k_trans(const float* __restrict__ ksrc, const float* __restrict__ vsrc,
             u16* __restrict__ dk0, u16* __restrict__ dk1, u16* __restrict__ dk2,
             u16* __restrict__ dv0, u16* __restrict__ dv1, u16* __restrict__ dv2,
             int ch)
{
  __shared__ float T[64][65];
  const int b = blockIdx.z & 7;
  const int sel = blockIdx.z >> 3;
  const int ct = blockIdx.x;  // c tile (0..15)
  const int dt = blockIdx.y;  // d tile (0..3)
  const int tid = threadIdx.x;
  const float* src = sel ? vsrc : ksrc;
  u16* d0 = sel ? dv0 : dk0;
  u16* d1 = sel ? dv1 : dk1;
  u16* d2 = sel ? dv2 : dk2;
  const float* S = src + ((size_t)b * LSEQ + (size_t)ch * CHK + ct * 64) * 256 + dt * 64;

#pragma unroll
  for (int qq = 0; qq < 4; ++qq) {
    const int flat = qq * 256 + tid;
    const int r = flat >> 4;           // c row
    const int cq = (flat & 15) * 4;    // d col
    const float4 v4 = *(const float4*)&S[(size_t)r * 256 + cq];
    T[r][cq + 0] = v4.x; T[r][cq + 1] = v4.y; T[r][cq + 2] = v4.z; T[r][cq + 3] = v4.w;
  }
  __syncthreads();

  u16* D0 = d0 + (size_t)b * (256 * CHK) + (size_t)(dt * 64) * CHK + ct * 64;
  u16* D1 = d1 + (size_t)b * (256 * CHK) + (size_t)(dt * 64) * CHK + ct * 64;
  u16* D2 = d2 + (size_t)b * (256 * CHK) + (size_t)(dt * 64) * CHK + ct * 64;
#pragma unroll
  for (int qq = 0; qq < 4; ++qq) {
    const int flat = qq * 256 + tid;
    const int rr = flat >> 4;          // d row
    const int cc = (flat & 15) * 4;    // c col
    ushort4 a, bq, cq4;
    u16* pa = &a.x; u16* pb = &bq.x; u16* pc = &cq4.x;
#pragma unroll
    for (int i = 0; i < 4; ++i) split3f(T[cc + i][rr], pa[i], pb[i], pc[i]);
    const size_t o = (size_t)rr * CHK + cc;
    *(ushort4*)&D0[o] = a;
    *(ushort4*)&D1[o] = bq;
    *(ushort4*)&D2[o] = cq4;
  }
}

// ---------------------------------------------------------------------------
// w1 transpose + scale + 3-limb split: wm1 [B][256][512] -> w1T [B][512][256]
// ---------------------------------------------------------------------------
__global__ __launch_bounds__(256)
void k_w1t(const float* __restrict__ wm1, const float* __restrict__ scales,
           u16* __restrict__ d0, u16* __restrict__ d1, u16* __restrict__ d2)
{
  __shared__ float T[64][65];
  const int b = blockIdx.z;
  const int ot = blockIdx.x;  // o tile (0..3)
  const int ht = blockIdx.y;  // h tile (0..7)
  const int tid = threadIdx.x;
  const float* S = wm1 + (size_t)b * (256 * 512) + (size_t)(ot * 64) * 512 + ht * 64;
  const float* sc = scales + 4096 + b * 256 + ot * 64;

#pragma unroll
  for (int qq = 0; qq < 4; ++qq) {
    const int flat = qq * 256 + tid;
    const int r = flat >> 4;
    const int cq = (flat & 15) * 4;
    const float s = sc[r];
    const float4 v4 = *(const float4*)&S[(size_t)r * 512 + cq];
    T[r][cq + 0] = v4.x * s; T[r][cq + 1] = v4.y * s; T[r][cq + 2] = v4.z * s; T[r][cq + 3] = v4.w * s;
  }
  __syncthreads();

  u16* D0 = d0 + (size_t)b * (512 * 256) + (size_t)(ht * 64) * 256 + ot * 64;
  u16* D1 = d1 + (size_t)b * (512 * 256) + (size_t)(ht * 64) * 256 + ot * 64;
  u16* D2 = d2 + (size_t)b * (512 * 256) + (size_t)(ht * 64) * 256 + ot * 64;
#pragma unroll
  for (int qq = 0; qq < 4; ++qq) {
    const int flat = qq * 256 + tid;
    const int rr = flat >> 4;
    const int cc = (flat & 15) * 4;
    ushort4 a, bq, cq4;
    u16* pa = &a.x; u16* pb = &bq.x; u16* pc = &cq4.x;
#pragma unroll
    for (int i = 0; i < 4; ++i) split3f(T[cc + i][rr], pa[i], pb[i], pc[i]);
    const size_t o = (size_t)rr * 256 + cc;
    *(ushort4*)&D0[o] = a;
    *(ushort4*)&D1[o] = bq;
    *(ushort4*)&D2[o] = cq4;
  }
}

// ---------------------------------------------------------------------------
// Initial scaled 3-limb split of wm0/wm1/wm2 (scales given; init uses 1.0)
// ---------------------------------------------------------------------------
__global__ __launch_bounds__(256)
void k_wsplit(const float* __restrict__ wm0, const float* __restrict__ wm1,
              const float* __restrict__ wm2, const float* __restrict__ scales,
              u16* __restrict__ a00, u16* __restrict__ a01, u16* __restrict__ a02,
              u16* __restrict__ a10, u16* __restrict__ a11, u16* __restrict__ a12,
              u16* __restrict__ a20, u16* __restrict__ a21, u16* __restrict__ a22)
{
  const size_t e4 = ((size_t)blockIdx.x * 256 + threadIdx.x) * 4;
  const float* src; u16 *d0, *d1, *d2; float s; size_t off;
  if (e4 < 1048576) {
    off = e4; src = wm0; d0 = a00; d1 = a01; d2 = a02;
    s = scales[off >> 8];
  } else if (e4 < 2097152) {
    off = e4 - 1048576; src = wm1; d0 = a10; d1 = a11; d2 = a12;
    s = scales[4096 + (off >> 9)];
  } else {
    off = e4 - 2097152; src = wm2; d0 = a20; d1 = a21; d2 = a22;
    s = scales[6144 + (off >> 8)];
  }
  const float4 v4 = *(const float4*)&src[off];
  const float xv[4] = {v4.x * s, v4.y * s, v4.z * s, v4.w * s};
  ushort4 a, bq, cq;
  u16* pa = &a.x; u16* pb = &bq.x; u16* pc = &cq.x;
#pragma unroll
  for (int t = 0; t < 4; ++t) split3f(xv[t], pa[t], pb[t], pc[t]);
  *(ushort4*)&d0[off] = a;
  *(ushort4*)&d1[off] = bq;
  *(ushort4*)&d2[off] = cq;
}

// ---------------------------------------------------------------------------
// Fused: per-row norm -> scale -> 3-limb split of all three weights.
// Row layout: [0,4096) w0 | [4096,6144) w1 | [6144,10240) w2
// Also writes scales[] (consumed by k_w1t).
// ---------------------------------------------------------------------------
__global__ __launch_bounds__(64)
void k_scalesplit(const float* __restrict__ wm0, const float* __restrict__ wm1,
                  const float* __restrict__ wm2, const float* __restrict__ wn,
                  float* __restrict__ scales,
                  u16* __restrict__ a00, u16* __restrict__ a01, u16* __restrict__ a02,
                  u16* __restrict__ a10, u16* __restrict__ a11, u16* __restrict__ a12,
                  u16* __restrict__ a20, u16* __restrict__ a21, u16* __restrict__ a22)
{
  const int row = blockIdx.x;
  const float* src; u16 *d0, *d1, *d2; int len; int r;
  if (row < 4096)      { r = row;        src = wm0; d0 = a00; d1 = a01; d2 = a02; len = 256; }
  else if (row < 6144) { r = row - 4096; src = wm1; d0 = a10; d1 = a11; d2 = a12; len = 512; }
  else                 { r = row - 6144; src = wm2; d0 = a20; d1 = a21; d2 = a22; len = 256; }
  const float* s = src + (size_t)r * len;
  float ss = 0.f;
  for (int i = threadIdx.x * 4; i < len; i += 256) {
    const float4 v4 = *(const float4*)&s[i];
    ss += v4.x * v4.x + v4.y * v4.y + v4.z * v4.z + v4.w * v4.w;
  }
#pragma unroll
  for (int off = 32; off > 0; off >>= 1) ss += __shfl_down(ss, off);
  ss = __shfl(ss, 0);
  const float scale = wn[row] / (sqrtf(ss) + 1e-5f);
  if (threadIdx.x == 0) scales[row] = scale;
  for (int i = threadIdx.x * 4; i < len; i += 256) {
    const float4 v4 = *(const float4*)&s[i];
    const float xv[4] = {v4.x * scale, v4.y * scale, v4.z * scale, v4.w * scale};
    ushort4 a, bq, cq;
    u16* pa = &a.x; u16* pb = &bq.x; u16* pc = &cq.x;
#pragma unroll
    for (int t = 0; t < 4; ++t) split3f(xv[t], pa[t], pb[t], pc[t]);
    const size_t o = (size_t)r * len + i;
    *(ushort4*)&d0[o] = a;
    *(ushort4*)&d1[o] = bq;
    *(ushort4*)&d2[o] = cq;
  }
}

// init: wm = w, wn = row norms, scales = 1
__global__ __launch_bounds__(64)
void k_init(const float* __restrict__ w0, const float* __restrict__ w1,
            const float* __restrict__ w2,
            float* __restrict__ wm0, float* __restrict__ wm1, float* __restrict__ wm2,
            float* __restrict__ wn, float* __restrict__ scales)
{
  const int row = blockIdx.x;
  const float* src; float* dst; int len; int r;
  if (row < 4096)      { r = row;        src = w0; dst = wm0; len = 256; }
  else if (row < 6144) { r = row - 4096; src = w1; dst = wm1; len = 512; }
  else                 { r = row - 6144; src = w2; dst = wm2; len = 256; }
  const float* s = src + (size_t)r * len;
  float* d = dst + (size_t)r * len;
  float ss = 0.f;
  for (int i = threadIdx.x; i < len; i += 64) {
    const float v = s[i];
    d[i] = v;
    ss += v * v;
  }
#pragma unroll
  for (int off = 32; off > 0; off >>= 1) ss += __shfl_down(ss, off);
  if (threadIdx.x == 0) {
    wn[row] = sqrtf(ss);
    scales[row] = 1.f;
  }
}

// ---------------------------------------------------------------------------
extern "C" void kernel_launch(void* const* d_in, const int* in_sizes, int n_in,
                              void* d_out, int out_size, void* d_ws, size_t ws_size,
                              hipStream_t stream)
{
  const float* w0  = (const float*)d_in[0];
  const float* w1  = (const float*)d_in[1];
  const float* w2  = (const float*)d_in[2];
  const float* q   = (const float*)d_in[3];
  const float* k   = (const float*)d_in[4];
  const float* v   = (const float*)d_in[5];
  const float* lr0 = (const float*)d_in[6];
  const float* lr1 = (const float*)d_in[7];
  const float* lr2 = (const float*)d_in[8];
  float* out = (float*)d_out;

  float* p = (float*)d_ws;
  size_t o = 0;
  auto AF = [&](size_t n) { float* r = p + o; o += n; return r; };
  auto AH = [&](size_t n) { u16* r = (u16*)(p + o); o += n / 2; return r; };

  constexpr long WL = 1048576;   // weight limb stride (u16)
  constexpr long XL = 2097152;   // input-chunk limb stride (u16)
  constexpr long HL = 4194304;   // hidden-sized limb stride (u16)

  float* wm0 = AF(1048576);
  float* wm1 = AF(1048576);
  float* wm2 = AF(1048576);
  float* wn = AF(10240);
  float* scales = AF(10240);
  float* gT  = AF(4194304);
  float* hT  = AF(4194304);
  float* dhT = AF(4194304);
  u16* w0s  = AH(3 * WL);
  u16* w2s  = AH(3 * WL);
  u16* w1s  = AH(3 * WL);
  u16* w1Ts = AH(3 * WL);
  u16* qs   = AH(2 * XL);
  u16* ks3  = AH(3 * XL);
  u16* vs3  = AH(3 * XL);
  u16* gbs  = AH(3 * HL);
  u16* hbs  = AH(3 * HL);
  u16* hds  = AH(3 * HL);
  // stream-ordered aliases (producers launch strictly after consumers drain):
  u16* kTs  = ks3;   // k^T limbs overwrite k-split limbs after fwd GEMM
  u16* vTs  = vs3;   // v^T limbs overwrite v-split limbs after fwd GEMM
  u16* acts = gbs;   // act limbs (2) use gbs limbs 0,1 (dead until k_bwd)

  // init: wm = w, wn = row norms, scales = 1
  k_init<<<10240, 64, 0, stream>>>(w0, w1, w2, wm0, wm1, wm2, wn, scales);
  k_wsplit<<<3072, 256, 0, stream>>>(wm0, wm1, wm2, scales,
      w0s, w0s + WL, w0s + 2 * WL, w1s, w1s + WL, w1s + 2 * WL,
      w2s, w2s + WL, w2s + 2 * WL);
  k_w1t<<<dim3(4, 8, NB), 256, 0, stream>>>(wm1, scales,
      w1Ts, w1Ts + WL, w1Ts + 2 * WL);

  for (int ch = 0; ch < NCHK; ++ch) {
    const bool last = (ch == NCHK - 1);
    // input chunk splits (q only on last chunk)
    k_split3<<<dim3(2048, last ? 1 : 3), 256, 0, stream>>>(q, k, v,
        qs, qs + XL, ks3, ks3 + XL, ks3 + 2 * XL, vs3, vs3 + XL, vs3 + 2 * XL, ch);

    // apply: act = silu(q w0^T) * (q w2^T)   [dual-B, 2-limb, swiglu epilogue]
    k_gemm<128, 64, 64, 2, 2, 4, 0><<<512, 256, 0, stream>>>(
        qs, nullptr, w0s, w2s, XL, WL,
        nullptr, nullptr, acts, acts + HL,
        256, DH, 262144, 131072, (long)CHK * DH, /*NTX*/8, /*NTY*/8,
        nullptr, nullptr, 0, 0, nullptr, 0, 0, 0, 0, 0);
    // out = act w1^T
    k_gemm<128, 64, 64, 2, 0, 0, 0><<<256, 256, 0, stream>>>(
        acts, nullptr, w1s, nullptr, HL, WL,
        out + (size_t)ch * CHK * DOUT, nullptr, nullptr, nullptr,
        512, DOUT, (long)CHK * DH, 131072, (long)LSEQ * DOUT, /*NTX*/4, /*NTY*/8,
        nullptr, nullptr, 0, 0, nullptr, 0, 0, 0, 0, 0);

    if (last) break;

    // MERGED scan forward: job0 (dual-A): gT = w0 k^T, hT = w2 k^T
    //                      job1:          dhT = w1T v^T
    k_gemm<64, 64, 32, 3, 1, 1, 1><<<2048, 256, 0, stream>>>(
        w0s, w2s, ks3, nullptr, WL, XL,
        gT, hT, nullptr, nullptr,
        256, CHK, 131072, 262144, (long)DH * CHK, /*NTX*/16, /*NTY*/8,
        w1Ts, vs3, WL, XL, dhT, CHK, 131072, 262144, (long)DH * CHK, /*NTX2*/16);

    // elementwise backprop + lr scale + 3-limb split (transposed space)
    k_bwd<<<4096, 256, 0, stream>>>(gT, hT, dhT, lr0, lr1, lr2,
        gbs, gbs + HL, gbs + 2 * HL, hbs, hbs + HL, hbs + 2 * HL,
        hds, hds + HL, hds + 2 * HL, ch);

    // kT, vT (3-limb, transposed chunk) — alias writes AFTER consumers drained
    k_trans<<<dim3(16, 4, 16), 256, 0, stream>>>(k, v,
        kTs, kTs + XL, kTs + 2 * XL, vTs, vTs + XL, vTs + 2 * XL, ch);

    // MERGED dw: job0 (dual-A): wm0 += gb kT^T, wm2 += hb kT^T
    //            job1:          wm1 += vT hd^T
    k_gemm<64, 64, 32, 3, 1, 3, 1><<<512, 256, 0, stream>>>(
        gbs, hbs, kTs, nullptr, HL, XL,
        wm0, wm2, nullptr, nullptr,
        1024, DIN, (long)DH * CHK, (long)DIN * CHK, (long)DH * DIN, /*NTX*/4, /*NTY*/8,
        vTs, hds, XL, HL, wm1, DH, (long)DOUT * CHK, (long)DH * CHK,
        (long)DOUT * DH, /*NTX2*/8);

    // fused renorm + weight limb refresh, then w1T refresh
    k_scalesplit<<<10240, 64, 0, stream>>>(wm0, wm1, wm2, wn, scales,
        w0s, w0s + WL, w0s + 2 * WL, w1s, w1s + WL, w1s + 2 * WL,
        w2s, w2s + WL, w2s + 2 * WL);
    k_w1t<<<dim3(4, 8, NB), 256, 0, stream>>>(wm1, scales,
        w1Ts, w1Ts + WL, w1Ts + 2 * WL);
  }
}

// Round 6
// 1611.263 us; speedup vs baseline: 1.7545x; 1.1376x over previous
//
#include <hip/hip_runtime.h>
#include <cmath>

typedef unsigned short u16;
typedef __attribute__((ext_vector_type(8))) short short8;
typedef __attribute__((ext_vector_type(4))) float f32x4;

#define DEVINL __device__ __forceinline__

// Problem constants
constexpr int NB   = 8;
constexpr int LSEQ = 8192;
constexpr int DIN  = 256;
constexpr int DH   = 512;
constexpr int DOUT = 256;
constexpr int CHK  = 1024;
constexpr int NCHK = LSEQ / CHK;
constexpr int DWSPLIT = 4;            // split-K factor for dw GEMM
constexpr long PSTRIDE = 1048576;     // partial slice stride (f32 elements)

// ---------------------------------------------------------------------------
// bf16 limb splits (truncation; residual captured exactly by next limb)
// ---------------------------------------------------------------------------
DEVINL void split2f(float v, u16& h, u16& l) {
  unsigned u = __builtin_bit_cast(unsigned, v);
  u16 hh = (u16)(u >> 16);
  float fh = __builtin_bit_cast(float, (unsigned)hh << 16);
  float r = v - fh;
  h = hh;
  l = (u16)(__builtin_bit_cast(unsigned, r) >> 16);
}
DEVINL void split3f(float v, u16& h, u16& m, u16& l) {
  unsigned u = __builtin_bit_cast(unsigned, v);
  u16 hh = (u16)(u >> 16);
  float fh = __builtin_bit_cast(float, (unsigned)hh << 16);
  float r1 = v - fh;
  u16 mm = (u16)(__builtin_bit_cast(unsigned, r1) >> 16);
  float fm = __builtin_bit_cast(float, (unsigned)mm << 16);
  float r2 = r1 - fm;
  h = hh; m = mm;
  l = (u16)(__builtin_bit_cast(unsigned, r2) >> 16);
}

// async global->LDS, 16B per lane, wave-uniform LDS base
DEVINL void gl16(const u16* g, u16* l) {
  __builtin_amdgcn_global_load_lds(
      (const __attribute__((address_space(1))) unsigned int*)g,
      (__attribute__((address_space(3))) unsigned int*)l,
      16, 0, 0);
}

template<int BK> DEVINL int swz(int r) { return (BK == 64) ? (r & 7) : ((r >> 1) & 3); }

// ---------------------------------------------------------------------------
// Generic NT multi-limb MFMA GEMM, flat grid with XCD-aware mapping:
//   fid = blockIdx.x; batch = fid & 7  (all blocks of a batch -> one XCD's L2)
//   C[m][n] (+)= sum_k A[m][k] * B[n][k]      (operands [rows][K], bf16 limbs)
// DUAL: 0 single, 1 dual-A (A,D share B), 2 dual-B (B,E share A)
// EPI : 0 store f32 out0; 1 store out0,out1 (dual); 2 out0+=; 3 dual +=;
//       4 dual-B swiglu: act = silu(acc0)*acc1 -> split2 -> oh, ol
// MERGE=1: second single-A job (A2*B2 -> out2, same BM/BN/BK/K geometry)
// KSPLIT>1: K range split; block ksid handles [ksid*Klen, (ksid+1)*Klen);
//           output offset ksid*sKp (partials; EPI must be a store variant)
// ---------------------------------------------------------------------------
template<int BM, int BN, int BK, int NS, int DUAL, int EPI, int MERGE, int KSPLIT>
__global__ __launch_bounds__(256)
void k_gemm(const u16* A, const u16* D, const u16* B, const u16* E,
            long sLA, long sLB,
            float* __restrict__ out0, float* __restrict__ out1,
            u16* __restrict__ oh, u16* __restrict__ ol,
            int K, int Klen, long sKp, int ldo, long sAb, long sBb, long sOb,
            int NTX, int NTY,
            const u16* A2, const u16* B2, long sLA2, long sLB2,
            float* __restrict__ out2, int ldo2,
            long sA2b, long sB2b, long sO2b, int NTX2)
{
  constexpr int NA  = (DUAL == 1) ? 2 : 1;
  constexpr int NB_ = (DUAL == 2) ? 2 : 1;
  constexpr int NDUP = DUAL ? 2 : 1;
  constexpr int SLOTS = BK / 8;        // 16B slots per LDS row
  constexpr int RPC = 64 / SLOTS;      // rows per 1KB staging chunk
  constexpr int TBA = BM * BK;         // u16 elements per A tile
  constexpr int TBB = BN * BK;
  constexpr int NTA = NA * NS, NTB = NB_ * NS;
  constexpr int CPA = BM / RPC, CPB = BN / RPC;
  constexpr int NCHUNK = NTA * CPA + NTB * CPB;
  constexpr int WM = BM / 2, WN = BN / 2, FM = WM / 16, FN = WN / 16;
  constexpr int KSTEPS = BK / 32;

  __shared__ alignas(16) u16 lds[(NTA * BM + NTB * BN) * BK];

  // XCD-aware decode
  const int fid = blockIdx.x;
  const int b = fid & 7;
  int t = fid >> 3;
  int job = 0;
  if (MERGE) {
    if (t >= NTY * NTX * KSPLIT) { job = 1; t -= NTY * NTX * KSPLIT; }
  }
  const int tile = t / KSPLIT;
  const int ksid = t % KSPLIT;
  const int ntx = (MERGE && job) ? NTX2 : NTX;
  const int my = tile / ntx, nx = tile % ntx;
  const int m0 = my * BM;
  const int n0 = nx * BN;

  const int tid = threadIdx.x, wid = tid >> 6, ln = tid & 63;
  const int wm = wid >> 1, wn = wid & 1;

  const u16* Ap; const u16* Dp = nullptr; const u16* Bp; const u16* Ep = nullptr;
  long eLA, eLB; int eldo; long eOb;
  const size_t kof = (size_t)ksid * Klen;
  if (MERGE && job) {
    Ap = A2 + (size_t)b * sA2b + (size_t)m0 * K + kof;
    Bp = B2 + (size_t)b * sB2b + (size_t)n0 * K + kof;
    eLA = sLA2; eLB = sLB2; eldo = ldo2; eOb = sO2b;
  } else {
    Ap = A + (size_t)b * sAb + (size_t)m0 * K + kof;
    if (DUAL == 1) Dp = D + (size_t)b * sAb + (size_t)m0 * K + kof;
    Bp = B + (size_t)b * sBb + (size_t)n0 * K + kof;
    if (DUAL == 2) Ep = E + (size_t)b * sBb + (size_t)n0 * K + kof;
    eLA = sLA; eLB = sLB; eldo = ldo; eOb = sOb;
  }

  f32x4 acc[NDUP][FM][FN];
#pragma unroll
  for (int d = 0; d < NDUP; ++d)
#pragma unroll
    for (int i = 0; i < FM; ++i)
#pragma unroll
      for (int j = 0; j < FN; ++j)
        acc[d][i][j] = (f32x4){0.f, 0.f, 0.f, 0.f};

  const int crow = ln / SLOTS;
  const int cslot = ln % SLOTS;

#pragma unroll 1
  for (int k0 = 0; k0 < Klen; k0 += BK) {
    // ---- stage tiles (1KB per wave-instruction, linear LDS dest) ----
    for (int c = wid; c < NCHUNK; c += 4) {
      const u16* g;
      u16* ldst;
      if (c < NTA * CPA) {
        const int tl = c / CPA, rb = c % CPA;
        const int da = tl / NS, s = tl % NS;
        if (MERGE && job && da == 1) continue;   // job1 is single-A
        const int r = rb * RPC + crow;
        const int kb = cslot ^ swz<BK>(r);
        const u16* base = (NA == 2 && da == 1) ? Dp : Ap;
        g = base + (size_t)s * eLA + (size_t)r * K + k0 + kb * 8;
        ldst = lds + tl * TBA + rb * (RPC * BK);
      } else {
        const int c2 = c - NTA * CPA;
        const int tl = c2 / CPB, rb = c2 % CPB;
        const int db = tl / NS, s = tl % NS;
        const int r = rb * RPC + crow;
        const int kb = cslot ^ swz<BK>(r);
        const u16* base = (NB_ == 2 && db == 1) ? Ep : Bp;
        g = base + (size_t)s * eLB + (size_t)r * K + k0 + kb * 8;
        ldst = lds + NTA * TBA + tl * TBB + rb * (RPC * BK);
      }
      gl16(g, ldst);
    }
    __syncthreads();

    // ---- compute: sa-outer / sb-inner triangular product set (sa+sb<NS) ----
    const int ro = ln & 15, ko = ln >> 4;
#pragma unroll
    for (int ks = 0; ks < KSTEPS; ++ks) {
      const int kb = ks * 4 + ko;
#pragma unroll
      for (int sa = 0; sa < NS; ++sa) {
        short8 af_[NA][FM];
#pragma unroll
        for (int da = 0; da < NA; ++da) {
          if (MERGE && job && da == 1) continue;
#pragma unroll
          for (int im = 0; im < FM; ++im) {
            const int row = wm * WM + im * 16 + ro;
            const int phys = kb ^ swz<BK>(row);
            af_[da][im] = *(const short8*)(lds + (da * NS + sa) * TBA + row * BK + phys * 8);
          }
        }
#pragma unroll
        for (int sb = 0; sb + sa < NS; ++sb) {
          short8 bf_[NB_][FN];
#pragma unroll
          for (int db = 0; db < NB_; ++db)
#pragma unroll
            for (int in = 0; in < FN; ++in) {
              const int row = wn * WN + in * 16 + ro;
              const int phys = kb ^ swz<BK>(row);
              bf_[db][in] = *(const short8*)(lds + NTA * TBA + (db * NS + sb) * TBB + row * BK + phys * 8);
            }
#pragma unroll
          for (int d = 0; d < NDUP; ++d) {
            if (MERGE && job && d == 1) continue;
            const int da = (DUAL == 1) ? d : 0;
            const int db = (DUAL == 2) ? d : 0;
#pragma unroll
            for (int im = 0; im < FM; ++im)
#pragma unroll
              for (int in = 0; in < FN; ++in)
                acc[d][im][in] = __builtin_amdgcn_mfma_f32_16x16x32_bf16(
                    af_[da][im], bf_[db][in], acc[d][im][in], 0, 0, 0);
          }
        }
      }
    }
    __syncthreads();
  }

  // ---- epilogue (C/D: col = lane&15, row = (lane>>4)*4 + reg) ----
  const size_t kout = (size_t)ksid * sKp;
#pragma unroll
  for (int im = 0; im < FM; ++im)
#pragma unroll
    for (int in = 0; in < FN; ++in)
#pragma unroll
      for (int r = 0; r < 4; ++r) {
        const int row = m0 + wm * WM + im * 16 + (ln >> 4) * 4 + r;
        const int col = n0 + wn * WN + in * 16 + (ln & 15);
        const size_t o = kout + (size_t)b * eOb + (size_t)row * eldo + col;
        if (MERGE && job) {
          if (EPI == 1) out2[o] = acc[0][im][in][r];
          else          out2[o] += acc[0][im][in][r];
        } else if (EPI == 0) {
          out0[o] = acc[0][im][in][r];
        } else if (EPI == 1) {
          out0[o] = acc[0][im][in][r];
          out1[o] = acc[1][im][in][r];
        } else if (EPI == 2) {
          out0[o] += acc[0][im][in][r];
        } else if (EPI == 3) {
          out0[o] += acc[0][im][in][r];
          out1[o] += acc[1][im][in][r];
        } else {
          const float g = acc[0][im][in][r];
          const float h = acc[1][im][in][r];
          const float s = 1.f / (1.f + expf(-g));
          const float a = g * s * h;
          u16 hh, ll;
          split2f(a, hh, ll);
          oh[o] = hh;
          ol[o] = ll;
        }
      }
}

// ---------------------------------------------------------------------------
// Elementwise SwiGLU backprop in transposed space [B][DH][C], lr-scaled,
// 3-limb split outputs for the dw GEMMs.
// ---------------------------------------------------------------------------
__global__ __launch_bounds__(256)
void k_bwd(const float* __restrict__ gT, const float* __restrict__ hT,
           const float* __restrict__ dT,
           const float* __restrict__ lr0, const float* __restrict__ lr1,
           const float* __restrict__ lr2,
           u16* __restrict__ gb0, u16* __restrict__ gb1, u16* __restrict__ gb2,
           u16* __restrict__ hb0, u16* __restrict__ hb1, u16* __restrict__ hb2,
           u16* __restrict__ hd0, u16* __restrict__ hd1, u16* __restrict__ hd2,
           int ch)
{
  const size_t i4 = (size_t)blockIdx.x * 256 + threadIdx.x;
  const size_t base = i4 * 4;
  const int c = (int)(base & 1023);
  const size_t bh = base >> 10;
  const int b = (int)(bh >> 9);
  const size_t li = (size_t)b * LSEQ + (size_t)ch * CHK + c;

  const float4 g4 = *(const float4*)&gT[base];
  const float4 h4 = *(const float4*)&hT[base];
  const float4 d4 = *(const float4*)&dT[base];
  const float4 L0 = *(const float4*)&lr0[li];
  const float4 L1 = *(const float4*)&lr1[li];
  const float4 L2 = *(const float4*)&lr2[li];
  const float gv[4] = {g4.x, g4.y, g4.z, g4.w};
  const float hv[4] = {h4.x, h4.y, h4.z, h4.w};
  const float dv[4] = {d4.x, d4.y, d4.z, d4.w};
  const float l0v[4] = {L0.x, L0.y, L0.z, L0.w};
  const float l1v[4] = {L1.x, L1.y, L1.z, L1.w};
  const float l2v[4] = {L2.x, L2.y, L2.z, L2.w};

  ushort4 og0, og1, og2, oh0, oh1, oh2, od0, od1, od2;
  u16* pg0 = &og0.x; u16* pg1 = &og1.x; u16* pg2 = &og2.x;
  u16* ph0 = &oh0.x; u16* ph1 = &oh1.x; u16* ph2 = &oh2.x;
  u16* pd0 = &od0.x; u16* pd1 = &od1.x; u16* pd2 = &od2.x;
#pragma unroll
  for (int t = 0; t < 4; ++t) {
    const float g = gv[t];
    const float sig = 1.f / (1.f + expf(-g));
    const float sg = g * sig;
    const float hidden = sg * hv[t];
    const float dhbm = dv[t] * sg;
    const float dgrad = dv[t] * hv[t];
    const float dgba = dgrad * sig * (1.f + g * (1.f - sig));
    split3f(dgba * l0v[t], pg0[t], pg1[t], pg2[t]);
    split3f(dhbm * l2v[t], ph0[t], ph1[t], ph2[t]);
    split3f(hidden * l1v[t], pd0[t], pd1[t], pd2[t]);
  }
  *(ushort4*)&gb0[base] = og0; *(ushort4*)&gb1[base] = og1; *(ushort4*)&gb2[base] = og2;
  *(ushort4*)&hb0[base] = oh0; *(ushort4*)&hb1[base] = oh1; *(ushort4*)&hb2[base] = oh2;
  *(ushort4*)&hd0[base] = od0; *(ushort4*)&hd1[base] = od1; *(ushort4*)&hd2[base] = od2;
}

// ---------------------------------------------------------------------------
// q/k/v chunk splits (q: 2 limbs, k/v: 3 limbs); chunk buffers [B][CHK][256]
// gridDim.y = 3 normally; = 1 on last chunk (q only)
// ---------------------------------------------------------------------------
__global__ __launch_bounds__(256)
void k_split3(const float* __restrict__ q, const float* __restrict__ k,
              const float* __restrict__ v,
              u16* __restrict__ q0, u16* __restrict__ q1,
              u16* __restrict__ k0s, u16* __restrict__ k1s, u16* __restrict__ k2s,
              u16* __restrict__ v0s, u16* __restrict__ v1s, u16* __restrict__ v2s,
              int ch)
{
  const int sec = blockIdx.y;
  const size_t base = ((size_t)blockIdx.x * 256 + threadIdx.x) * 4;  // [0, 2M)
  const int b = (int)(base >> 18);
  const size_t rem = base & 0x3FFFF;
  const size_t soff = (size_t)b * (LSEQ * 256) + (size_t)ch * (CHK * 256) + rem;

  const float* src = (sec == 0) ? q : (sec == 1) ? k : v;
  const float4 x4 = *(const float4*)&src[soff];
  const float xv[4] = {x4.x, x4.y, x4.z, x4.w};

  if (sec == 0) {
    ushort4 a, bq;
    u16* pa = &a.x; u16* pb = &bq.x;
#pragma unroll
    for (int t = 0; t < 4; ++t) split2f(xv[t], pa[t], pb[t]);
    *(ushort4*)&q0[base] = a;
    *(ushort4*)&q1[base] = bq;
  } else {
    ushort4 a, bq, cq;
    u16* pa = &a.x; u16* pb = &bq.x; u16* pc = &cq.x;
#pragma unroll
    for (int t = 0; t < 4; ++t) split3f(xv[t], pa[t], pb[t], pc[t]);
    u16* d0 = (sec == 1) ? k0s : v0s;
    u16* d1 = (sec == 1) ? k1s : v1s;
    u16* d2 = (sec == 1) ? k2s : v2s;
    *(ushort4*)&d0[base] = a;
    *(ushort4*)&d1[base] = bq;
    *(ushort4*)&d2[base] = cq;
  }
}

// ---------------------------------------------------------------------------
// Tiled transpose + 3-limb split: src [B][LSEQ][256] chunk -> dst [B][256][CHK]
// gridDim.z = 16: z&7 = batch, z>>3 = source select (0 -> k->dK, 1 -> v->dV)
// ---------------------------------------------------------------------------
__global__ __launch_bounds__(256)
void k_trans(const float* __restrict__ ksrc, const float* __restrict__ vsrc,
             u16* __restrict__ dk0, u16* __restrict__ dk1, u16* __restrict__ dk2,
             u16* __restrict__ dv0, u16* __restrict__ dv1, u16* __restrict__ dv2,
             int ch)
{
  __shared__ float T[64][65];
  const int b = blockIdx.z & 7;
  const int sel = blockIdx.z >> 3;
  const int ct = blockIdx.x;  // c tile (0..15)
  const int dt = blockIdx.y;  // d tile (0..3)
  const int tid = threadIdx.x;
  const float* src = sel ? vsrc : ksrc;
  u16* d0 = sel ? dv0 : dk0;
  u16* d1 = sel ? dv1 : dk1;
  u16* d2 = sel ? dv2 : dk2;
  const float* S = src + ((size_t)b * LSEQ + (size_t)ch * CHK + ct * 64) * 256 + dt * 64;

#pragma unroll
  for (int qq = 0; qq < 4; ++qq) {
    const int flat = qq * 256 + tid;
    const int r = flat >> 4;           // c row
    const int cq = (flat & 15) * 4;    // d col
    const float4 v4 = *(const float4*)&S[(size_t)r * 256 + cq];
    T[r][cq + 0] = v4.x; T[r][cq + 1] = v4.y; T[r][cq + 2] = v4.z; T[r][cq + 3] = v4.w;
  }
  __syncthreads();

  u16* D0 = d0 + (size_t)b * (256 * CHK) + (size_t)(dt * 64) * CHK + ct * 64;
  u16* D1 = d1 + (size_t)b * (256 * CHK) + (size_t)(dt * 64) * CHK + ct * 64;
  u16* D2 = d2 + (size_t)b * (256 * CHK) + (size_t)(dt * 64) * CHK + ct * 64;
#pragma unroll
  for (int qq = 0; qq < 4; ++qq) {
    const int flat = qq * 256 + tid;
    const int rr = flat >> 4;          // d row
    const int cc = (flat & 15) * 4;    // c col
    ushort4 a, bq, cq4;
    u16* pa = &a.x; u16* pb = &bq.x; u16* pc = &cq4.x;
#pragma unroll
    for (int i = 0; i < 4; ++i) split3f(T[cc + i][rr], pa[i], pb[i], pc[i]);
    const size_t o = (size_t)rr * CHK + cc;
    *(ushort4*)&D0[o] = a;
    *(ushort4*)&D1[o] = bq;
    *(ushort4*)&D2[o] = cq4;
  }
}

// ---------------------------------------------------------------------------
// w1 transpose + scale + 3-limb split: wm1 [B][256][512] -> w1T [B][512][256]
// ---------------------------------------------------------------------------
__global__ __launch_bounds__(256)
void k_w1t(const float* __restrict__ wm1, const float* __restrict__ scales,
           u16* __restrict__ d0, u16* __restrict__ d1, u16* __restrict__ d2)
{
  __shared__ float T[64][65];
  const int b = blockIdx.z;
  const int ot = blockIdx.x;  // o tile (0..3)
  const int ht = blockIdx.y;  // h tile (0..7)
  const int tid = threadIdx.x;
  const float* S = wm1 + (size_t)b * (256 * 512) + (size_t)(ot * 64) * 512 + ht * 64;
  const float* sc = scales + 4096 + b * 256 + ot * 64;

#pragma unroll
  for (int qq = 0; qq < 4; ++qq) {
    const int flat = qq * 256 + tid;
    const int r = flat >> 4;
    const int cq = (flat & 15) * 4;
    const float s = sc[r];
    const float4 v4 = *(const float4*)&S[(size_t)r * 512 + cq];
    T[r][cq + 0] = v4.x * s; T[r][cq + 1] = v4.y * s; T[r][cq + 2] = v4.z * s; T[r][cq + 3] = v4.w * s;
  }
  __syncthreads();

  u16* D0 = d0 + (size_t)b * (512 * 256) + (size_t)(ht * 64) * 256 + ot * 64;
  u16* D1 = d1 + (size_t)b * (512 * 256) + (size_t)(ht * 64) * 256 + ot * 64;
  u16* D2 = d2 + (size_t)b * (512 * 256) + (size_t)(ht * 64) * 256 + ot * 64;
#pragma unroll
  for (int qq = 0; qq < 4; ++qq) {
    const int flat = qq * 256 + tid;
    const int rr = flat >> 4;
    const int cc = (flat & 15) * 4;
    ushort4 a, bq, cq4;
    u16* pa = &a.x; u16* pb = &bq.x; u16* pc = &cq4.x;
#pragma unroll
    for (int i = 0; i < 4; ++i) split3f(T[cc + i][rr], pa[i], pb[i], pc[i]);
    const size_t o = (size_t)rr * 256 + cc;
    *(ushort4*)&D0[o] = a;
    *(ushort4*)&D1[o] = bq;
    *(ushort4*)&D2[o] = cq4;
  }
}

// ---------------------------------------------------------------------------
// Initial scaled 3-limb split of wm0/wm1/wm2 (init path, scales = 1)
// ---------------------------------------------------------------------------
__global__ __launch_bounds__(256)
void k_wsplit(const float* __restrict__ wm0, const float* __restrict__ wm1,
              const float* __restrict__ wm2, const float* __restrict__ scales,
              u16* __restrict__ a00, u16* __restrict__ a01, u16* __restrict__ a02,
              u16* __restrict__ a10, u16* __restrict__ a11, u16* __restrict__ a12,
              u16* __restrict__ a20, u16* __restrict__ a21, u16* __restrict__ a22)
{
  const size_t e4 = ((size_t)blockIdx.x * 256 + threadIdx.x) * 4;
  const float* src; u16 *d0, *d1, *d2; float s; size_t off;
  if (e4 < 1048576) {
    off = e4; src = wm0; d0 = a00; d1 = a01; d2 = a02;
    s = scales[off >> 8];
  } else if (e4 < 2097152) {
    off = e4 - 1048576; src = wm1; d0 = a10; d1 = a11; d2 = a12;
    s = scales[4096 + (off >> 9)];
  } else {
    off = e4 - 2097152; src = wm2; d0 = a20; d1 = a21; d2 = a22;
    s = scales[6144 + (off >> 8)];
  }
  const float4 v4 = *(const float4*)&src[off];
  const float xv[4] = {v4.x * s, v4.y * s, v4.z * s, v4.w * s};
  ushort4 a, bq, cq;
  u16* pa = &a.x; u16* pb = &bq.x; u16* pc = &cq.x;
#pragma unroll
  for (int t = 0; t < 4; ++t) split3f(xv[t], pa[t], pb[t], pc[t]);
  *(ushort4*)&d0[off] = a;
  *(ushort4*)&d1[off] = bq;
  *(ushort4*)&d2[off] = cq;
}

// ---------------------------------------------------------------------------
// Fused: accumulate split-K dw partials into wm, per-row norm -> scale ->
// 3-limb split of all three weights. Row layout: [0,4096) w0 | [4096,6144) w1
// | [6144,10240) w2. Partials: p* = [DWSPLIT][1M] f32 slices.
// ---------------------------------------------------------------------------
__global__ __launch_bounds__(64)
void k_scalesplit(float* __restrict__ wm0, float* __restrict__ wm1,
                  float* __restrict__ wm2,
                  const float* __restrict__ p0, const float* __restrict__ p1,
                  const float* __restrict__ p2,
                  const float* __restrict__ wn, float* __restrict__ scales,
                  u16* __restrict__ a00, u16* __restrict__ a01, u16* __restrict__ a02,
                  u16* __restrict__ a10, u16* __restrict__ a11, u16* __restrict__ a12,
                  u16* __restrict__ a20, u16* __restrict__ a21, u16* __restrict__ a22)
{
  const int row = blockIdx.x;
  float* wm; const float* pp; u16 *d0, *d1, *d2; int len; int r;
  if (row < 4096)      { r = row;        wm = wm0; pp = p0; d0 = a00; d1 = a01; d2 = a02; len = 256; }
  else if (row < 6144) { r = row - 4096; wm = wm1; pp = p1; d0 = a10; d1 = a11; d2 = a12; len = 512; }
  else                 { r = row - 6144; wm = wm2; pp = p2; d0 = a20; d1 = a21; d2 = a22; len = 256; }
  float* wrow = wm + (size_t)r * len;
  const float* prow = pp + (size_t)r * len;

  float vals[8];
  int cnt = 0;
  float ss = 0.f;
  for (int i = threadIdx.x * 4; i < len; i += 256) {
    float4 w4 = *(const float4*)&wrow[i];
    float acc4[4] = {w4.x, w4.y, w4.z, w4.w};
#pragma unroll
    for (int s = 0; s < DWSPLIT; ++s) {
      const float4 q4 = *(const float4*)&prow[(size_t)s * PSTRIDE + i];
      acc4[0] += q4.x; acc4[1] += q4.y; acc4[2] += q4.z; acc4[3] += q4.w;
    }
    *(float4*)&wrow[i] = make_float4(acc4[0], acc4[1], acc4[2], acc4[3]);
#pragma unroll
    for (int t = 0; t < 4; ++t) { vals[cnt + t] = acc4[t]; ss += acc4[t] * acc4[t]; }
    cnt += 4;
  }
#pragma unroll
  for (int off = 32; off > 0; off >>= 1) ss += __shfl_down(ss, off);
  ss = __shfl(ss, 0);
  const float scale = wn[row] / (sqrtf(ss) + 1e-5f);
  if (threadIdx.x == 0) scales[row] = scale;
  cnt = 0;
  for (int i = threadIdx.x * 4; i < len; i += 256) {
    ushort4 a, bq, cq;
    u16* pa = &a.x; u16* pb = &bq.x; u16* pc = &cq.x;
#pragma unroll
    for (int t = 0; t < 4; ++t) split3f(vals[cnt + t] * scale, pa[t], pb[t], pc[t]);
    cnt += 4;
    const size_t o = (size_t)r * len + i;
    *(ushort4*)&d0[o] = a;
    *(ushort4*)&d1[o] = bq;
    *(ushort4*)&d2[o] = cq;
  }
}

// init: wm = w, wn = row norms, scales = 1
__global__ __launch_bounds__(64)
void k_init(const float* __restrict__ w0, const float* __restrict__ w1,
            const float* __restrict__ w2,
            float* __restrict__ wm0, float* __restrict__ wm1, float* __restrict__ wm2,
            float* __restrict__ wn, float* __restrict__ scales)
{
  const int row = blockIdx.x;
  const float* src; float* dst; int len; int r;
  if (row < 4096)      { r = row;        src = w0; dst = wm0; len = 256; }
  else if (row < 6144) { r = row - 4096; src = w1; dst = wm1; len = 512; }
  else                 { r = row - 6144; src = w2; dst = wm2; len = 256; }
  const float* s = src + (size_t)r * len;
  float* d = dst + (size_t)r * len;
  float ss = 0.f;
  for (int i = threadIdx.x; i < len; i += 64) {
    const float v = s[i];
    d[i] = v;
    ss += v * v;
  }
#pragma unroll
  for (int off = 32; off > 0; off >>= 1) ss += __shfl_down(ss, off);
  if (threadIdx.x == 0) {
    wn[row] = sqrtf(ss);
    scales[row] = 1.f;
  }
}

// ---------------------------------------------------------------------------
extern "C" void kernel_launch(void* const* d_in, const int* in_sizes, int n_in,
                              void* d_out, int out_size, void* d_ws, size_t ws_size,
                              hipStream_t stream)
{
  const float* w0  = (const float*)d_in[0];
  const float* w1  = (const float*)d_in[1];
  const float* w2  = (const float*)d_in[2];
  const float* q   = (const float*)d_in[3];
  const float* k   = (const float*)d_in[4];
  const float* v   = (const float*)d_in[5];
  const float* lr0 = (const float*)d_in[6];
  const float* lr1 = (const float*)d_in[7];
  const float* lr2 = (const float*)d_in[8];
  float* out = (float*)d_out;

  float* p = (float*)d_ws;
  size_t o = 0;
  auto AF = [&](size_t n) { float* r = p + o; o += n; return r; };
  auto AH = [&](size_t n) { u16* r = (u16*)(p + o); o += n / 2; return r; };

  constexpr long WL = 1048576;   // weight limb stride (u16)
  constexpr long XL = 2097152;   // input-chunk limb stride (u16)
  constexpr long HL = 4194304;   // hidden-sized limb stride (u16)

  float* wm0 = AF(1048576);
  float* wm1 = AF(1048576);
  float* wm2 = AF(1048576);
  float* wn = AF(10240);
  float* scales = AF(10240);
  float* gT  = AF(4194304);   // also: dw0 split-K partials [4][1M]
  float* hT  = AF(4194304);   // also: dw2 partials
  float* dhT = AF(4194304);   // also: dw1 partials
  u16* w0s  = AH(3 * WL);
  u16* w2s  = AH(3 * WL);
  u16* w1s  = AH(3 * WL);
  u16* w1Ts = AH(3 * WL);
  u16* qs   = AH(2 * XL);
  u16* ks3  = AH(3 * XL);
  u16* vs3  = AH(3 * XL);
  u16* gbs  = AH(3 * HL);
  u16* hbs  = AH(3 * HL);
  u16* hds  = AH(3 * HL);
  // stream-ordered aliases (producers launch strictly after consumers drain):
  u16* kTs  = ks3;   // k^T limbs overwrite k-split limbs after fwd GEMM
  u16* vTs  = vs3;   // v^T limbs overwrite v-split limbs after fwd GEMM
  u16* acts = gbs;   // act limbs (2) use gbs limbs 0,1 (dead until k_bwd)

  // init: wm = w, wn = row norms, scales = 1
  k_init<<<10240, 64, 0, stream>>>(w0, w1, w2, wm0, wm1, wm2, wn, scales);
  k_wsplit<<<3072, 256, 0, stream>>>(wm0, wm1, wm2, scales,
      w0s, w0s + WL, w0s + 2 * WL, w1s, w1s + WL, w1s + 2 * WL,
      w2s, w2s + WL, w2s + 2 * WL);
  k_w1t<<<dim3(4, 8, NB), 256, 0, stream>>>(wm1, scales,
      w1Ts, w1Ts + WL, w1Ts + 2 * WL);

  for (int ch = 0; ch < NCHK; ++ch) {
    const bool last = (ch == NCHK - 1);
    // input chunk splits (q only on last chunk)
    k_split3<<<dim3(2048, last ? 1 : 3), 256, 0, stream>>>(q, k, v,
        qs, qs + XL, ks3, ks3 + XL, ks3 + 2 * XL, vs3, vs3 + XL, vs3 + 2 * XL, ch);

    // apply: act = silu(q w0^T) * (q w2^T)   [dual-B, 2-limb, swiglu epilogue]
    k_gemm<128, 64, 64, 2, 2, 4, 0, 1><<<512, 256, 0, stream>>>(
        qs, nullptr, w0s, w2s, XL, WL,
        nullptr, nullptr, acts, acts + HL,
        256, 256, 0, DH, 262144, 131072, (long)CHK * DH, /*NTX*/8, /*NTY*/8,
        nullptr, nullptr, 0, 0, nullptr, 0, 0, 0, 0, 0);
    // out = act w1^T
    k_gemm<128, 64, 64, 2, 0, 0, 0, 1><<<256, 256, 0, stream>>>(
        acts, nullptr, w1s, nullptr, HL, WL,
        out + (size_t)ch * CHK * DOUT, nullptr, nullptr, nullptr,
        512, 512, 0, DOUT, (long)CHK * DH, 131072, (long)LSEQ * DOUT,
        /*NTX*/4, /*NTY*/8,
        nullptr, nullptr, 0, 0, nullptr, 0, 0, 0, 0, 0);

    if (last) break;

    // MERGED scan forward (128x128): job0 dual-A: gT = w0 k^T, hT = w2 k^T
    //                                 job1:       dhT = w1T v^T
    k_gemm<128, 128, 32, 3, 1, 1, 1, 1><<<512, 256, 0, stream>>>(
        w0s, w2s, ks3, nullptr, WL, XL,
        gT, hT, nullptr, nullptr,
        256, 256, 0, CHK, 131072, 262144, (long)DH * CHK, /*NTX*/8, /*NTY*/4,
        w1Ts, vs3, WL, XL, dhT, CHK, 131072, 262144, (long)DH * CHK, /*NTX2*/8);

    // elementwise backprop + lr scale + 3-limb split (transposed space)
    k_bwd<<<4096, 256, 0, stream>>>(gT, hT, dhT, lr0, lr1, lr2,
        gbs, gbs + HL, gbs + 2 * HL, hbs, hbs + HL, hbs + 2 * HL,
        hds, hds + HL, hds + 2 * HL, ch);

    // kT, vT (3-limb, transposed chunk) — alias writes AFTER consumers drained
    k_trans<<<dim3(16, 4, 16), 256, 0, stream>>>(k, v,
        kTs, kTs + XL, kTs + 2 * XL, vTs, vTs + XL, vTs + 2 * XL, ch);

    // MERGED dw (128x128, split-K=4, partial stores into gT/hT/dhT):
    //   job0 dual-A: dw0_part = gb kT^T, dw2_part = hb kT^T
    //   job1:        dw1_part = vT hd^T
    k_gemm<128, 128, 32, 3, 1, 1, 1, DWSPLIT><<<512, 256, 0, stream>>>(
        gbs, hbs, kTs, nullptr, HL, XL,
        gT, hT, nullptr, nullptr,
        1024, 256, PSTRIDE, DIN, (long)DH * CHK, (long)DIN * CHK,
        (long)DH * DIN, /*NTX*/2, /*NTY*/4,
        vTs, hds, XL, HL, dhT, DH, (long)DOUT * CHK, (long)DH * CHK,
        (long)DOUT * DH, /*NTX2*/4);

    // fused partial-sum + renorm + weight limb refresh, then w1T refresh
    k_scalesplit<<<10240, 64, 0, stream>>>(wm0, wm1, wm2, gT, dhT, hT,
        wn, scales,
        w0s, w0s + WL, w0s + 2 * WL, w1s, w1s + WL, w1s + 2 * WL,
        w2s, w2s + WL, w2s + 2 * WL);
    k_w1t<<<dim3(4, 8, NB), 256, 0, stream>>>(wm1, scales,
        w1Ts, w1Ts + WL, w1Ts + 2 * WL);
  }
}